// Round 6
// baseline (105.847 us; speedup 1.0000x reference)
//
#include <hip/hip_runtime.h>
#include <hip/hip_bf16.h>

// Problem: B=2, T=2048, E=256, S=128, W=8, H=150
// pairs@w1 = gi@w1a + gj@w1b + (gi*gj)@w1c
// All MLP GEMMs on MFMA (bf16 in, f32 acc).
// Round-6: identical to round 5 except the LDS overlay bug fix in attn/uvm:
// red moved 5376 -> 10752 (h1 is [32][168] bf16 = 10752 B; red overlapped
// rows 16..17 of h1 -> float bits read as bf16 (exp 0xFE -> ~e38 garbage)).

typedef __bf16 bf16;
typedef __attribute__((ext_vector_type(8))) short v8s;
typedef __attribute__((ext_vector_type(8))) __bf16 v8bf;
typedef __attribute__((ext_vector_type(4))) float v4f;

#define MFMA_BF16(A, B, C) __builtin_amdgcn_mfma_f32_16x16x32_bf16((A), (B), (C), 0, 0, 0)

__device__ __forceinline__ v8bf mul_cvt8(float4 xa, float4 xb, float4 sa, float4 sb) {
    v8bf w;
    w[0] = (bf16)(xa.x * sa.x); w[1] = (bf16)(xa.y * sa.y);
    w[2] = (bf16)(xa.z * sa.z); w[3] = (bf16)(xa.w * sa.w);
    w[4] = (bf16)(xb.x * sb.x); w[5] = (bf16)(xb.y * sb.y);
    w[6] = (bf16)(xb.z * sb.z); w[7] = (bf16)(xb.w * sb.w);
    return w;
}
__device__ __forceinline__ v8bf cvt8(float4 xa, float4 xb) {
    v8bf w;
    w[0] = (bf16)xa.x; w[1] = (bf16)xa.y; w[2] = (bf16)xa.z; w[3] = (bf16)xa.w;
    w[4] = (bf16)xb.x; w[5] = (bf16)xb.y; w[6] = (bf16)xb.z; w[7] = (bf16)xb.w;
    return w;
}

// ---------------- prep (unchanged) ----------------
__global__ __launch_bounds__(256) void prep_kernel(
    const float* __restrict__ pw1, const float* __restrict__ pw2,
    const float* __restrict__ aw1, const float* __restrict__ aw2,
    const float* __restrict__ mw1, const float* __restrict__ mw2,
    const float* __restrict__ pb1, const float* __restrict__ pb2, const float* __restrict__ pw3,
    const float* __restrict__ ab1, const float* __restrict__ ab2, const float* __restrict__ aw3,
    const float* __restrict__ mb1, const float* __restrict__ mb2, const float* __restrict__ mw3,
    bf16* __restrict__ w1cT, bf16* __restrict__ w2pT,
    bf16* __restrict__ w1aT, bf16* __restrict__ w2aT, bf16* __restrict__ w2mT,
    bf16* __restrict__ wuvmT, float* __restrict__ bias)
{
    int idx = blockIdx.x * 256 + threadIdx.x;
    if (idx < 147456) {
        int h = idx / 768, e = idx % 768;
        w1cT[idx] = (bf16)((h < 150) ? pw1[(1536 + e) * 150 + h] : 0.f);
    } else if (idx < 178176) {
        int j = idx - 147456; int n = j / 160, k = j % 160;
        w2pT[j] = (bf16)((n < 150 && k < 150) ? pw2[k * 150 + n] : 0.f);
    } else if (idx < 227328) {
        int j = idx - 178176; int h = j / 256, e = j % 256;
        w1aT[j] = (bf16)((h < 150) ? aw1[e * 150 + h] : 0.f);
    } else if (idx < 258048) {
        int j = idx - 227328; int n = j / 160, k = j % 160;
        w2aT[j] = (bf16)((n < 150 && k < 150) ? aw2[k * 150 + n] : 0.f);
    } else if (idx < 288768) {
        int j = idx - 258048; int n = j / 160, k = j % 160;
        w2mT[j] = (bf16)((n < 150 && k < 150) ? mw2[k * 150 + n] : 0.f);
    } else if (idx < 731136) {
        int j = idx - 288768; int s = j / 147456; int r = j % 147456;
        int h = r / 768, e = r % 768;
        float v = 0.f;
        if (h < 150) {
            if (s == 0)      v = pw1[e * 150 + h];
            else if (s == 1) v = pw1[(768 + e) * 150 + h];
            else             v = mw1[e * 150 + h];
        }
        wuvmT[j] = (bf16)v;
    } else if (idx < 732864) {
        int j = idx - 731136; int arr = j / 192, h = j % 192;
        const float* src;
        switch (arr) {
            case 0: src = pb1; break; case 1: src = pb2; break; case 2: src = pw3; break;
            case 3: src = ab1; break; case 4: src = ab2; break; case 5: src = aw3; break;
            case 6: src = mb1; break; case 7: src = mb2; break; default: src = mw3; break;
        }
        bias[j] = (h < 150) ? src[h] : 0.f;
    }
}

// ---------------- build g (unchanged) ----------------
__global__ __launch_bounds__(256) void build_g_kernel(
    const float* __restrict__ emb, const int* __restrict__ spans,
    const float* __restrict__ attns, float* __restrict__ g)
{
    int blk = blockIdx.x;
    int b = blk >> 7;
    int t0 = spans[blk];
    int e = threadIdx.x;
    const float* eb = emb + ((size_t)(b * 2048 + t0)) * 256 + e;
    const float* at = attns + b * 2048 + t0;
    float start = eb[0];
    float endv  = eb[7 * 256];
    float wsum = 0.f;
#pragma unroll
    for (int w = 0; w < 8; ++w) wsum = fmaf(eb[w * 256], at[w], wsum);
    g[(size_t)blk * 768 + e]       = start;
    g[(size_t)blk * 768 + 256 + e] = endv;
    g[(size_t)blk * 768 + 512 + e] = wsum;
}

// ============ M=32 skeleton (attn / uvm): LDS a 2x32x72 | b 2x192x72 ============
//  smem 64512 B; h1 [32][168] overlays bytes 0..10752; red @10752 (AFTER h1).
#define A32_ELEMS 2304
#define B_ELEMS   13824

// ---------------- attn MLP: 128 blocks, M=32, K=256(NC=4), N=192pad ----------------
__global__ __launch_bounds__(512, 4) void attn_mfma_kernel(
    const float* __restrict__ emb,
    const bf16* __restrict__ w1aT, const bf16* __restrict__ w2aT,
    const float* __restrict__ b1p, const float* __restrict__ b2p,
    const float* __restrict__ w3p, const float* __restrict__ b3,
    float* __restrict__ attns)
{
    __shared__ __attribute__((aligned(16))) char smem[64512];
    bf16*  a_lds  = (bf16*)smem;
    bf16*  b_lds  = (bf16*)(smem + 9216);
    bf16*  h1_lds = (bf16*)smem;
    float* red    = (float*)(smem + 10752);   // FIX: past h1 (was 5376, overlapped)

    const int m0  = blockIdx.x * 32;
    const int tid = threadIdx.x;
    const int lane = tid & 63;
    const int wm = (tid >> 6) >> 2, wn = (tid >> 6) & 3;
    const int l15 = lane & 15, lk = (lane >> 4) * 8;
    const int aj = tid >> 3, ae = (tid & 7) * 8;      // A-stage role (tid<256)
    const float* gA = emb + (size_t)(m0 + aj) * 256 + ae;

    {   // stage chunk 0 directly
        if (tid < 256) {
            float4 x0 = *(const float4*)(gA + 0), x1 = *(const float4*)(gA + 4);
            *(v8bf*)(a_lds + aj * 72 + ae) = cvt8(x0, x1);
        }
#pragma unroll
        for (int s2 = 0; s2 < 3; ++s2) {
            const int li = tid + s2 * 512, row = li >> 3, c8 = (li & 7) * 8;
            *(uint4*)(b_lds + row * 72 + c8) = *(const uint4*)(w1aT + row * 256 + c8);
        }
    }
    float4 xq[2][2];
    uint4  bq[2][3];
    {   // issue chunk 1 -> set 1
        if (tid < 256) { xq[1][0] = *(const float4*)(gA + 64); xq[1][1] = *(const float4*)(gA + 68); }
#pragma unroll
        for (int s2 = 0; s2 < 3; ++s2) {
            const int li = tid + s2 * 512, row = li >> 3, c8 = (li & 7) * 8;
            bq[1][s2] = *(const uint4*)(w1aT + row * 256 + 64 + c8);
        }
    }
    __syncthreads();

    v4f acc[3];
#pragma unroll
    for (int nf = 0; nf < 3; ++nf) acc[nf] = (v4f){0.f, 0.f, 0.f, 0.f};

#pragma unroll
    for (int c = 0; c < 4; ++c) {
        if (c + 2 < 4) {        // issue chunk c+2 -> set c&1
            const int e0 = (c + 2) * 64;
            if (tid < 256) { xq[c & 1][0] = *(const float4*)(gA + e0); xq[c & 1][1] = *(const float4*)(gA + e0 + 4); }
#pragma unroll
            for (int s2 = 0; s2 < 3; ++s2) {
                const int li = tid + s2 * 512, row = li >> 3, c8 = (li & 7) * 8;
                bq[c & 1][s2] = *(const uint4*)(w1aT + row * 256 + e0 + c8);
            }
        }
        const bf16* ab = a_lds + (c & 1) * A32_ELEMS;
        const bf16* bb = b_lds + (c & 1) * B_ELEMS;
#pragma unroll
        for (int ks = 0; ks < 2; ++ks) {
            const int kb = ks * 32 + lk;
            v8s af = *(const v8s*)&ab[(wm * 16 + l15) * 72 + kb];
            v8s bfr[3];
#pragma unroll
            for (int nf = 0; nf < 3; ++nf)
                bfr[nf] = *(const v8s*)&bb[(wn * 48 + nf * 16 + l15) * 72 + kb];
#pragma unroll
            for (int nf = 0; nf < 3; ++nf)
                acc[nf] = MFMA_BF16(af, bfr[nf], acc[nf]);
        }
        if (c + 1 < 4) {        // write chunk c+1 from set (c&1)^1
            const int p = (c & 1) ^ 1;
            if (tid < 256)
                *(v8bf*)(a_lds + ((c + 1) & 1) * A32_ELEMS + aj * 72 + ae) = cvt8(xq[p][0], xq[p][1]);
#pragma unroll
            for (int s2 = 0; s2 < 3; ++s2) {
                const int li = tid + s2 * 512, row = li >> 3, c8 = (li & 7) * 8;
                *(uint4*)(b_lds + ((c + 1) & 1) * B_ELEMS + row * 72 + c8) = bq[p][s2];
            }
        }
        __syncthreads();
    }

    {   // layer1 epilogue -> h1
        const float b10 = b1p[wn * 48 + 0  + l15];
        const float b11 = b1p[wn * 48 + 16 + l15];
        const float b12 = b1p[wn * 48 + 32 + l15];
#pragma unroll
        for (int r = 0; r < 4; ++r) {
            const int jl = wm * 16 + (lane >> 4) * 4 + r;
            bf16* hrow = h1_lds + jl * 168 + wn * 48 + l15;
            hrow[0] = (bf16)fmaxf(acc[0][r] + b10, 0.f);
            if (wn < 3) {
                hrow[16] = (bf16)fmaxf(acc[1][r] + b11, 0.f);
                hrow[32] = (bf16)fmaxf(acc[2][r] + b12, 0.f);
            }
        }
    }
    __syncthreads();

    v4f acc2[3];
#pragma unroll
    for (int nf = 0; nf < 3; ++nf) acc2[nf] = (v4f){0.f, 0.f, 0.f, 0.f};
#pragma unroll
    for (int ks = 0; ks < 5; ++ks) {
        const int kb = ks * 32 + lk;
        v8s af = *(const v8s*)&h1_lds[(wm * 16 + l15) * 168 + kb];
        v8s bfr[3];
#pragma unroll
        for (int nf = 0; nf < 3; ++nf)
            bfr[nf] = *(const v8s*)&w2aT[(size_t)(wn * 48 + nf * 16 + l15) * 160 + kb];
#pragma unroll
        for (int nf = 0; nf < 3; ++nf)
            acc2[nf] = MFMA_BF16(af, bfr[nf], acc2[nf]);
    }

    const float b2v0 = b2p[wn * 48 + 0  + l15], w3v0 = w3p[wn * 48 + 0  + l15];
    const float b2v1 = b2p[wn * 48 + 16 + l15], w3v1 = w3p[wn * 48 + 16 + l15];
    const float b2v2 = b2p[wn * 48 + 32 + l15], w3v2 = w3p[wn * 48 + 32 + l15];
#pragma unroll
    for (int r = 0; r < 4; ++r) {
        float p = fmaxf(acc2[0][r] + b2v0, 0.f) * w3v0
                + fmaxf(acc2[1][r] + b2v1, 0.f) * w3v1
                + fmaxf(acc2[2][r] + b2v2, 0.f) * w3v2;
        p += __shfl_xor(p, 1);
        p += __shfl_xor(p, 2);
        p += __shfl_xor(p, 4);
        p += __shfl_xor(p, 8);
        if (l15 == 0) {
            const int jl = wm * 16 + (lane >> 4) * 4 + r;
            red[jl * 4 + wn] = p;
        }
    }
    __syncthreads();
    if (tid < 32) {
        attns[m0 + tid] = red[tid * 4 + 0] + red[tid * 4 + 1]
                        + red[tid * 4 + 2] + red[tid * 4 + 3] + b3[0];
    }
}

// ---------------- uvm: 24 blocks = 3 sections x 8 M-tiles of 32, K=768(NC=12) ----------------
__global__ __launch_bounds__(512, 4) void uvm_mfma_kernel(
    const float* __restrict__ g, const bf16* __restrict__ wuvmT,
    const bf16* __restrict__ w2mT,
    const float* __restrict__ pb1p, const float* __restrict__ mb1p,
    const float* __restrict__ mb2p, const float* __restrict__ mw3p,
    const float* __restrict__ mb3,
    float* __restrict__ u_pad, float* __restrict__ v_pad, float* __restrict__ ment)
{
    __shared__ __attribute__((aligned(16))) char smem[64512];
    bf16*  a_lds  = (bf16*)smem;
    bf16*  b_lds  = (bf16*)(smem + 9216);
    bf16*  h1_lds = (bf16*)smem;
    float* red    = (float*)(smem + 10752);   // FIX: past h1 (was 5376, overlapped)

    const int sect = blockIdx.x >> 3;          // 0=u, 1=v, 2=ment
    const int m0   = (blockIdx.x & 7) * 32;
    const bf16* Bw = wuvmT + (size_t)sect * 147456;
    const int tid = threadIdx.x;
    const int lane = tid & 63;
    const int wm = (tid >> 6) >> 2, wn = (tid >> 6) & 3;
    const int l15 = lane & 15, lk = (lane >> 4) * 8;
    const int aj = tid >> 3, ae = (tid & 7) * 8;
    const float* gA = g + (size_t)(m0 + aj) * 768 + ae;

    {   // stage chunk 0
        if (tid < 256) {
            float4 x0 = *(const float4*)(gA + 0), x1 = *(const float4*)(gA + 4);
            *(v8bf*)(a_lds + aj * 72 + ae) = cvt8(x0, x1);
        }
#pragma unroll
        for (int s2 = 0; s2 < 3; ++s2) {
            const int li = tid + s2 * 512, row = li >> 3, c8 = (li & 7) * 8;
            *(uint4*)(b_lds + row * 72 + c8) = *(const uint4*)(Bw + row * 768 + c8);
        }
    }
    float4 xq[2][2];
    uint4  bq[2][3];
    {   // issue chunk 1 -> set 1
        if (tid < 256) { xq[1][0] = *(const float4*)(gA + 64); xq[1][1] = *(const float4*)(gA + 68); }
#pragma unroll
        for (int s2 = 0; s2 < 3; ++s2) {
            const int li = tid + s2 * 512, row = li >> 3, c8 = (li & 7) * 8;
            bq[1][s2] = *(const uint4*)(Bw + row * 768 + 64 + c8);
        }
    }
    __syncthreads();

    v4f acc[3];
#pragma unroll
    for (int nf = 0; nf < 3; ++nf) acc[nf] = (v4f){0.f, 0.f, 0.f, 0.f};

#pragma unroll
    for (int c = 0; c < 12; ++c) {
        if (c + 2 < 12) {
            const int e0 = (c + 2) * 64;
            if (tid < 256) { xq[c & 1][0] = *(const float4*)(gA + e0); xq[c & 1][1] = *(const float4*)(gA + e0 + 4); }
#pragma unroll
            for (int s2 = 0; s2 < 3; ++s2) {
                const int li = tid + s2 * 512, row = li >> 3, c8 = (li & 7) * 8;
                bq[c & 1][s2] = *(const uint4*)(Bw + row * 768 + e0 + c8);
            }
        }
        const bf16* ab = a_lds + (c & 1) * A32_ELEMS;
        const bf16* bb = b_lds + (c & 1) * B_ELEMS;
#pragma unroll
        for (int ks = 0; ks < 2; ++ks) {
            const int kb = ks * 32 + lk;
            v8s af = *(const v8s*)&ab[(wm * 16 + l15) * 72 + kb];
            v8s bfr[3];
#pragma unroll
            for (int nf = 0; nf < 3; ++nf)
                bfr[nf] = *(const v8s*)&bb[(wn * 48 + nf * 16 + l15) * 72 + kb];
#pragma unroll
            for (int nf = 0; nf < 3; ++nf)
                acc[nf] = MFMA_BF16(af, bfr[nf], acc[nf]);
        }
        if (c + 1 < 12) {
            const int p = (c & 1) ^ 1;
            if (tid < 256)
                *(v8bf*)(a_lds + ((c + 1) & 1) * A32_ELEMS + aj * 72 + ae) = cvt8(xq[p][0], xq[p][1]);
#pragma unroll
            for (int s2 = 0; s2 < 3; ++s2) {
                const int li = tid + s2 * 512, row = li >> 3, c8 = (li & 7) * 8;
                *(uint4*)(b_lds + ((c + 1) & 1) * B_ELEMS + row * 72 + c8) = bq[p][s2];
            }
        }
        __syncthreads();
    }

    if (sect < 2) {
        float* dst = (sect == 0) ? u_pad : v_pad;
        const float bb0 = (sect == 0) ? pb1p[wn * 48 + 0  + l15] : 0.f;
        const float bb1 = (sect == 0) ? pb1p[wn * 48 + 16 + l15] : 0.f;
        const float bb2 = (sect == 0) ? pb1p[wn * 48 + 32 + l15] : 0.f;
#pragma unroll
        for (int r = 0; r < 4; ++r) {
            const int jl = wm * 16 + (lane >> 4) * 4 + r;
            float* drow = dst + (size_t)(m0 + jl) * 192 + wn * 48 + l15;
            drow[0]  = acc[0][r] + bb0;
            drow[16] = acc[1][r] + bb1;
            drow[32] = acc[2][r] + bb2;
        }
        return;
    }

    // ---- ment tail ----
    {
        const float b10 = mb1p[wn * 48 + 0  + l15];
        const float b11 = mb1p[wn * 48 + 16 + l15];
        const float b12 = mb1p[wn * 48 + 32 + l15];
#pragma unroll
        for (int r = 0; r < 4; ++r) {
            const int jl = wm * 16 + (lane >> 4) * 4 + r;
            bf16* hrow = h1_lds + jl * 168 + wn * 48 + l15;
            hrow[0] = (bf16)fmaxf(acc[0][r] + b10, 0.f);
            if (wn < 3) {
                hrow[16] = (bf16)fmaxf(acc[1][r] + b11, 0.f);
                hrow[32] = (bf16)fmaxf(acc[2][r] + b12, 0.f);
            }
        }
    }
    __syncthreads();

    v4f acc2[3];
#pragma unroll
    for (int nf = 0; nf < 3; ++nf) acc2[nf] = (v4f){0.f, 0.f, 0.f, 0.f};
#pragma unroll
    for (int ks = 0; ks < 5; ++ks) {
        const int kb = ks * 32 + lk;
        v8s af = *(const v8s*)&h1_lds[(wm * 16 + l15) * 168 + kb];
        v8s bfr[3];
#pragma unroll
        for (int nf = 0; nf < 3; ++nf)
            bfr[nf] = *(const v8s*)&w2mT[(size_t)(wn * 48 + nf * 16 + l15) * 160 + kb];
#pragma unroll
        for (int nf = 0; nf < 3; ++nf)
            acc2[nf] = MFMA_BF16(af, bfr[nf], acc2[nf]);
    }

    const float b2v0 = mb2p[wn * 48 + 0  + l15], w3v0 = mw3p[wn * 48 + 0  + l15];
    const float b2v1 = mb2p[wn * 48 + 16 + l15], w3v1 = mw3p[wn * 48 + 16 + l15];
    const float b2v2 = mb2p[wn * 48 + 32 + l15], w3v2 = mw3p[wn * 48 + 32 + l15];
#pragma unroll
    for (int r = 0; r < 4; ++r) {
        float p = fmaxf(acc2[0][r] + b2v0, 0.f) * w3v0
                + fmaxf(acc2[1][r] + b2v1, 0.f) * w3v1
                + fmaxf(acc2[2][r] + b2v2, 0.f) * w3v2;
        p += __shfl_xor(p, 1);
        p += __shfl_xor(p, 2);
        p += __shfl_xor(p, 4);
        p += __shfl_xor(p, 8);
        if (l15 == 0) {
            const int jl = wm * 16 + (lane >> 4) * 4 + r;
            red[jl * 4 + wn] = p;
        }
    }
    __syncthreads();
    if (tid < 32) {
        ment[m0 + tid] = red[tid * 4 + 0] + red[tid * 4 + 1]
                       + red[tid * 4 + 2] + red[tid * 4 + 3] + mb3[0];
    }
}

// ---------------- pair: 512 blocks = (b, i, j-half), M=64, depth-2 pipeline ----------------
#define A64_ELEMS 4608
__global__ __launch_bounds__(512, 4) void pair_mfma_kernel(
    const float* __restrict__ g,
    const float* __restrict__ u_pad, const float* __restrict__ v_pad,
    const bf16* __restrict__ w1cT, const bf16* __restrict__ w2T,
    const float* __restrict__ b2_pad, const float* __restrict__ w3_pad,
    const float* __restrict__ pb3, const float* __restrict__ ment,
    float* __restrict__ out)
{
    __shared__ __attribute__((aligned(16))) char smem[76800];
    bf16*  a_lds  = (bf16*)smem;             // 2 x 64 x 72
    bf16*  b_lds  = (bf16*)(smem + 18432);   // 2 x 192 x 72
    float* gi_s   = (float*)(smem + 73728);  // 768 f32
    bf16*  h1_lds = (bf16*)smem;             // 64 x 168 overlay (21504 B)
    float* red    = (float*)(smem + 22528);

    const int blk = blockIdx.x;              // b*256 + i*2 + half
    const int b = blk >> 8;
    const int i = (blk >> 1) & 127;
    const int half = blk & 1;
    const int row_i = b * 128 + i;
    const int jg0 = b * 128 + half * 64;
    const int tid = threadIdx.x;
    const int lane = tid & 63;
    const int wm = (tid >> 6) >> 2, wn = (tid >> 6) & 3;
    const int l15 = lane & 15, lk = (lane >> 4) * 8;
    const int aj = tid >> 3, ae = (tid & 7) * 8;
    const float* gA = g + (size_t)(jg0 + aj) * 768 + ae;

    if (tid < 192)
        *(float4*)&gi_s[tid * 4] = *(const float4*)&g[(size_t)row_i * 768 + tid * 4];
    __syncthreads();

    {   // stage chunk 0
        float4 x0 = *(const float4*)(gA + 0), x1 = *(const float4*)(gA + 4);
        const float* gp = gi_s + ae;
        float4 s0 = *(const float4*)(gp + 0), s1 = *(const float4*)(gp + 4);
        *(v8bf*)(a_lds + aj * 72 + ae) = mul_cvt8(x0, x1, s0, s1);
#pragma unroll
        for (int s2 = 0; s2 < 3; ++s2) {
            const int li = tid + s2 * 512, row = li >> 3, c8 = (li & 7) * 8;
            *(uint4*)(b_lds + row * 72 + c8) = *(const uint4*)(w1cT + row * 768 + c8);
        }
    }
    float4 xq[2][2];
    uint4  bq[2][3];
    {   // issue chunk 1 -> set 1
        xq[1][0] = *(const float4*)(gA + 64);
        xq[1][1] = *(const float4*)(gA + 68);
#pragma unroll
        for (int s2 = 0; s2 < 3; ++s2) {
            const int li = tid + s2 * 512, row = li >> 3, c8 = (li & 7) * 8;
            bq[1][s2] = *(const uint4*)(w1cT + row * 768 + 64 + c8);
        }
    }
    __syncthreads();

    v4f acc[2][3];
#pragma unroll
    for (int mf = 0; mf < 2; ++mf)
#pragma unroll
        for (int nf = 0; nf < 3; ++nf) acc[mf][nf] = (v4f){0.f, 0.f, 0.f, 0.f};

#pragma unroll
    for (int c = 0; c < 12; ++c) {
        if (c + 2 < 12) {       // issue chunk c+2 -> set c&1
            const int e0 = (c + 2) * 64;
            xq[c & 1][0] = *(const float4*)(gA + e0);
            xq[c & 1][1] = *(const float4*)(gA + e0 + 4);
#pragma unroll
            for (int s2 = 0; s2 < 3; ++s2) {
                const int li = tid + s2 * 512, row = li >> 3, c8 = (li & 7) * 8;
                bq[c & 1][s2] = *(const uint4*)(w1cT + row * 768 + e0 + c8);
            }
        }
        const bf16* ab = a_lds + (c & 1) * A64_ELEMS;
        const bf16* bb = b_lds + (c & 1) * B_ELEMS;
#pragma unroll
        for (int ks = 0; ks < 2; ++ks) {
            const int kb = ks * 32 + lk;
            v8s af[2], bfr[3];
#pragma unroll
            for (int mf = 0; mf < 2; ++mf)
                af[mf] = *(const v8s*)&ab[(wm * 32 + mf * 16 + l15) * 72 + kb];
#pragma unroll
            for (int nf = 0; nf < 3; ++nf)
                bfr[nf] = *(const v8s*)&bb[(wn * 48 + nf * 16 + l15) * 72 + kb];
#pragma unroll
            for (int mf = 0; mf < 2; ++mf)
#pragma unroll
                for (int nf = 0; nf < 3; ++nf)
                    acc[mf][nf] = MFMA_BF16(af[mf], bfr[nf], acc[mf][nf]);
        }
        if (c + 1 < 12) {       // write chunk c+1 from set (c&1)^1
            const int p = (c & 1) ^ 1;
            const float* gp = gi_s + (c + 1) * 64 + ae;
            float4 s0 = *(const float4*)(gp + 0), s1 = *(const float4*)(gp + 4);
            *(v8bf*)(a_lds + ((c + 1) & 1) * A64_ELEMS + aj * 72 + ae) =
                mul_cvt8(xq[p][0], xq[p][1], s0, s1);
#pragma unroll
            for (int s2 = 0; s2 < 3; ++s2) {
                const int li = tid + s2 * 512, row = li >> 3, c8 = (li & 7) * 8;
                *(uint4*)(b_lds + ((c + 1) & 1) * B_ELEMS + row * 72 + c8) = bq[p][s2];
            }
        }
        __syncthreads();
    }

    {   // layer1 epilogue: h1 = relu(cross + u_i + v_j)
        const float uh0 = u_pad[row_i * 192 + wn * 48 + 0  + l15];
        const float uh1 = u_pad[row_i * 192 + wn * 48 + 16 + l15];
        const float uh2 = u_pad[row_i * 192 + wn * 48 + 32 + l15];
#pragma unroll
        for (int mf = 0; mf < 2; ++mf) {
#pragma unroll
            for (int r = 0; r < 4; ++r) {
                const int jl = wm * 32 + mf * 16 + (lane >> 4) * 4 + r;
                const float* vrow = v_pad + (size_t)(jg0 + jl) * 192 + wn * 48 + l15;
                const float v0 = acc[mf][0][r] + uh0 + vrow[0];
                const float v1 = acc[mf][1][r] + uh1 + vrow[16];
                const float v2 = acc[mf][2][r] + uh2 + vrow[32];
                bf16* hrow = h1_lds + jl * 168 + wn * 48 + l15;
                hrow[0] = (bf16)fmaxf(v0, 0.f);
                if (wn < 3) {
                    hrow[16] = (bf16)fmaxf(v1, 0.f);
                    hrow[32] = (bf16)fmaxf(v2, 0.f);
                }
            }
        }
    }
    __syncthreads();

    v4f acc2[2][3];
#pragma unroll
    for (int mf = 0; mf < 2; ++mf)
#pragma unroll
        for (int nf = 0; nf < 3; ++nf) acc2[mf][nf] = (v4f){0.f, 0.f, 0.f, 0.f};
#pragma unroll
    for (int ks = 0; ks < 5; ++ks) {
        const int kb = ks * 32 + lk;
        v8s af[2], bfr[3];
#pragma unroll
        for (int mf = 0; mf < 2; ++mf)
            af[mf] = *(const v8s*)&h1_lds[(wm * 32 + mf * 16 + l15) * 168 + kb];
#pragma unroll
        for (int nf = 0; nf < 3; ++nf)
            bfr[nf] = *(const v8s*)&w2T[(size_t)(wn * 48 + nf * 16 + l15) * 160 + kb];
#pragma unroll
        for (int mf = 0; mf < 2; ++mf)
#pragma unroll
            for (int nf = 0; nf < 3; ++nf)
                acc2[mf][nf] = MFMA_BF16(af[mf], bfr[nf], acc2[mf][nf]);
    }

    const float b2v0 = b2_pad[wn * 48 + 0  + l15], w3v0 = w3_pad[wn * 48 + 0  + l15];
    const float b2v1 = b2_pad[wn * 48 + 16 + l15], w3v1 = w3_pad[wn * 48 + 16 + l15];
    const float b2v2 = b2_pad[wn * 48 + 32 + l15], w3v2 = w3_pad[wn * 48 + 32 + l15];
#pragma unroll
    for (int mf = 0; mf < 2; ++mf) {
#pragma unroll
        for (int r = 0; r < 4; ++r) {
            float p = fmaxf(acc2[mf][0][r] + b2v0, 0.f) * w3v0
                    + fmaxf(acc2[mf][1][r] + b2v1, 0.f) * w3v1
                    + fmaxf(acc2[mf][2][r] + b2v2, 0.f) * w3v2;
            p += __shfl_xor(p, 1);
            p += __shfl_xor(p, 2);
            p += __shfl_xor(p, 4);
            p += __shfl_xor(p, 8);
            if (l15 == 0) {
                const int jl = wm * 32 + mf * 16 + (lane >> 4) * 4 + r;
                red[jl * 4 + wn] = p;
            }
        }
    }
    __syncthreads();
    if (tid < 64) {
        const float s = red[tid * 4 + 0] + red[tid * 4 + 1] + red[tid * 4 + 2] + red[tid * 4 + 3];
        out[(size_t)b * 16384 + (size_t)i * 128 + half * 64 + tid] =
            (s + pb3[0] + ment[row_i] + ment[b * 128 + half * 64 + tid]) * (1.f / 3.f);
    }
}

extern "C" void kernel_launch(void* const* d_in, const int* in_sizes, int n_in,
                              void* d_out, int out_size, void* d_ws, size_t ws_size,
                              hipStream_t stream)
{
    const float* emb   = (const float*)d_in[0];
    const int*   spans = (const int*)d_in[1];
    const float* aw1 = (const float*)d_in[2];
    const float* ab1 = (const float*)d_in[3];
    const float* aw2 = (const float*)d_in[4];
    const float* ab2 = (const float*)d_in[5];
    const float* aw3 = (const float*)d_in[6];
    const float* ab3 = (const float*)d_in[7];
    const float* mw1 = (const float*)d_in[8];
    const float* mb1 = (const float*)d_in[9];
    const float* mw2 = (const float*)d_in[10];
    const float* mb2 = (const float*)d_in[11];
    const float* mw3 = (const float*)d_in[12];
    const float* mb3 = (const float*)d_in[13];
    const float* pw1 = (const float*)d_in[14];
    const float* pb1 = (const float*)d_in[15];
    const float* pw2 = (const float*)d_in[16];
    const float* pb2 = (const float*)d_in[17];
    const float* pw3 = (const float*)d_in[18];
    const float* pb3 = (const float*)d_in[19];

    float* ws    = (float*)d_ws;
    float* attns = ws;              // 4096
    float* g     = ws + 4096;       // 196608
    float* ment  = ws + 200704;     // 256
    float* u_pad = ws + 200960;     // 49152
    float* v_pad = ws + 250112;     // 49152
    float* bias  = ws + 299264;     // 1728
    float* pb1p = bias;         float* pb2p = bias + 192;  float* pw3p = bias + 384;
    float* ab1p = bias + 576;   float* ab2p = bias + 768;  float* aw3p = bias + 960;
    float* mb1p = bias + 1152;  float* mb2p = bias + 1344; float* mw3p = bias + 1536;
    bf16* w1cT  = (bf16*)(ws + 300992);
    bf16* w2pT  = (bf16*)(ws + 374720);
    bf16* w1aT  = (bf16*)(ws + 390080);
    bf16* w2aT  = (bf16*)(ws + 414656);
    bf16* w2mT  = (bf16*)(ws + 430016);
    bf16* wuvmT = (bf16*)(ws + 445376);

    prep_kernel<<<2863, 256, 0, stream>>>(pw1, pw2, aw1, aw2, mw1, mw2,
                                          pb1, pb2, pw3, ab1, ab2, aw3, mb1, mb2, mw3,
                                          w1cT, w2pT, w1aT, w2aT, w2mT, wuvmT, bias);
    attn_mfma_kernel<<<128, 512, 0, stream>>>(emb, w1aT, w2aT, ab1p, ab2p, aw3p, ab3, attns);
    build_g_kernel<<<256, 256, 0, stream>>>(emb, spans, attns, g);
    uvm_mfma_kernel<<<24, 512, 0, stream>>>(g, wuvmT, w2mT, pb1p, mb1p, mb2p, mw3p, mb3,
                                            u_pad, v_pad, ment);
    pair_mfma_kernel<<<512, 512, 0, stream>>>(g, u_pad, v_pad, w1cT, w2pT,
                                              pb2p, pw3p, pb3, ment, (float*)d_out);
}

// Round 7
// 62.679 us; speedup vs baseline: 1.6887x; 1.6887x over previous
//
#include <hip/hip_runtime.h>
#include <hip/hip_bf16.h>

// Problem: B=2, T=2048, E=256, S=128, W=8, H=150
// pairs@w1 = gi@w1a + gj@w1b + (gi*gj)@w1c
// All MLP GEMMs on MFMA (bf16 in, f32 acc).
// Round-7: revert K-loops to depth-1 prefetch with NAMED in-loop registers
// (round-6's xq[c&1]/bq[c&1] arrays didn't unroll -> scratch spill, 53MB
// writes/dispatch, MfmaUtil 7%). Keep: attn M=32 (128 blk), uvm M=32 (24 blk),
// pair M=64 (512 blk), red @10752 fix, launch_bounds(512,4).

typedef __bf16 bf16;
typedef __attribute__((ext_vector_type(8))) short v8s;
typedef __attribute__((ext_vector_type(8))) __bf16 v8bf;
typedef __attribute__((ext_vector_type(4))) float v4f;

#define MFMA_BF16(A, B, C) __builtin_amdgcn_mfma_f32_16x16x32_bf16((A), (B), (C), 0, 0, 0)

__device__ __forceinline__ v8bf mul_cvt8(float4 xa, float4 xb, float4 sa, float4 sb) {
    v8bf w;
    w[0] = (bf16)(xa.x * sa.x); w[1] = (bf16)(xa.y * sa.y);
    w[2] = (bf16)(xa.z * sa.z); w[3] = (bf16)(xa.w * sa.w);
    w[4] = (bf16)(xb.x * sb.x); w[5] = (bf16)(xb.y * sb.y);
    w[6] = (bf16)(xb.z * sb.z); w[7] = (bf16)(xb.w * sb.w);
    return w;
}
__device__ __forceinline__ v8bf cvt8(float4 xa, float4 xb) {
    v8bf w;
    w[0] = (bf16)xa.x; w[1] = (bf16)xa.y; w[2] = (bf16)xa.z; w[3] = (bf16)xa.w;
    w[4] = (bf16)xb.x; w[5] = (bf16)xb.y; w[6] = (bf16)xb.z; w[7] = (bf16)xb.w;
    return w;
}

// ---------------- prep (unchanged) ----------------
__global__ __launch_bounds__(256) void prep_kernel(
    const float* __restrict__ pw1, const float* __restrict__ pw2,
    const float* __restrict__ aw1, const float* __restrict__ aw2,
    const float* __restrict__ mw1, const float* __restrict__ mw2,
    const float* __restrict__ pb1, const float* __restrict__ pb2, const float* __restrict__ pw3,
    const float* __restrict__ ab1, const float* __restrict__ ab2, const float* __restrict__ aw3,
    const float* __restrict__ mb1, const float* __restrict__ mb2, const float* __restrict__ mw3,
    bf16* __restrict__ w1cT, bf16* __restrict__ w2pT,
    bf16* __restrict__ w1aT, bf16* __restrict__ w2aT, bf16* __restrict__ w2mT,
    bf16* __restrict__ wuvmT, float* __restrict__ bias)
{
    int idx = blockIdx.x * 256 + threadIdx.x;
    if (idx < 147456) {
        int h = idx / 768, e = idx % 768;
        w1cT[idx] = (bf16)((h < 150) ? pw1[(1536 + e) * 150 + h] : 0.f);
    } else if (idx < 178176) {
        int j = idx - 147456; int n = j / 160, k = j % 160;
        w2pT[j] = (bf16)((n < 150 && k < 150) ? pw2[k * 150 + n] : 0.f);
    } else if (idx < 227328) {
        int j = idx - 178176; int h = j / 256, e = j % 256;
        w1aT[j] = (bf16)((h < 150) ? aw1[e * 150 + h] : 0.f);
    } else if (idx < 258048) {
        int j = idx - 227328; int n = j / 160, k = j % 160;
        w2aT[j] = (bf16)((n < 150 && k < 150) ? aw2[k * 150 + n] : 0.f);
    } else if (idx < 288768) {
        int j = idx - 258048; int n = j / 160, k = j % 160;
        w2mT[j] = (bf16)((n < 150 && k < 150) ? mw2[k * 150 + n] : 0.f);
    } else if (idx < 731136) {
        int j = idx - 288768; int s = j / 147456; int r = j % 147456;
        int h = r / 768, e = r % 768;
        float v = 0.f;
        if (h < 150) {
            if (s == 0)      v = pw1[e * 150 + h];
            else if (s == 1) v = pw1[(768 + e) * 150 + h];
            else             v = mw1[e * 150 + h];
        }
        wuvmT[j] = (bf16)v;
    } else if (idx < 732864) {
        int j = idx - 731136; int arr = j / 192, h = j % 192;
        const float* src;
        switch (arr) {
            case 0: src = pb1; break; case 1: src = pb2; break; case 2: src = pw3; break;
            case 3: src = ab1; break; case 4: src = ab2; break; case 5: src = aw3; break;
            case 6: src = mb1; break; case 7: src = mb2; break; default: src = mw3; break;
        }
        bias[j] = (h < 150) ? src[h] : 0.f;
    }
}

// ---------------- build g (unchanged) ----------------
__global__ __launch_bounds__(256) void build_g_kernel(
    const float* __restrict__ emb, const int* __restrict__ spans,
    const float* __restrict__ attns, float* __restrict__ g)
{
    int blk = blockIdx.x;
    int b = blk >> 7;
    int t0 = spans[blk];
    int e = threadIdx.x;
    const float* eb = emb + ((size_t)(b * 2048 + t0)) * 256 + e;
    const float* at = attns + b * 2048 + t0;
    float start = eb[0];
    float endv  = eb[7 * 256];
    float wsum = 0.f;
#pragma unroll
    for (int w = 0; w < 8; ++w) wsum = fmaf(eb[w * 256], at[w], wsum);
    g[(size_t)blk * 768 + e]       = start;
    g[(size_t)blk * 768 + 256 + e] = endv;
    g[(size_t)blk * 768 + 512 + e] = wsum;
}

#define A32_ELEMS 2304   // 32*72
#define A64_ELEMS 4608   // 64*72
#define B_ELEMS   13824  // 192*72

// ---------------- attn MLP: 128 blocks, M=32, K=256(NC=4), N=192pad ----------------
__global__ __launch_bounds__(512, 4) void attn_mfma_kernel(
    const float* __restrict__ emb,
    const bf16* __restrict__ w1aT, const bf16* __restrict__ w2aT,
    const float* __restrict__ b1p, const float* __restrict__ b2p,
    const float* __restrict__ w3p, const float* __restrict__ b3,
    float* __restrict__ attns)
{
    __shared__ __attribute__((aligned(16))) char smem[64512];
    bf16*  a_lds  = (bf16*)smem;              // 2 x 32 x 72
    bf16*  b_lds  = (bf16*)(smem + 9216);     // 2 x 192 x 72
    bf16*  h1_lds = (bf16*)smem;              // [32][168] overlay (10752 B)
    float* red    = (float*)(smem + 10752);

    const int m0  = blockIdx.x * 32;
    const int tid = threadIdx.x;
    const int lane = tid & 63;
    const int wm = (tid >> 6) >> 2, wn = (tid >> 6) & 3;
    const int l15 = lane & 15, lk = (lane >> 4) * 8;
    const int aj = tid >> 3, ae = (tid & 7) * 8;   // A role (tid<256): row aj, col ae
    const int br = tid >> 3, bc = (tid & 7) * 8;   // B role: rows br,br+64,br+128, col bc
    const float* gA = emb + (size_t)(m0 + (aj & 31)) * 256 + ae;

    {   // stage chunk 0 directly
        if (tid < 256) {
            float4 x0 = *(const float4*)(gA + 0), x1 = *(const float4*)(gA + 4);
            *(v8bf*)(a_lds + aj * 72 + ae) = cvt8(x0, x1);
        }
#pragma unroll
        for (int s2 = 0; s2 < 3; ++s2) {
            const int row = br + s2 * 64;
            *(uint4*)(b_lds + row * 72 + bc) = *(const uint4*)(w1aT + row * 256 + bc);
        }
    }
    __syncthreads();

    v4f acc[3];
#pragma unroll
    for (int nf = 0; nf < 3; ++nf) acc[nf] = (v4f){0.f, 0.f, 0.f, 0.f};

    for (int c = 0; c < 4; ++c) {
        float4 x0, x1;
        uint4 b0, b1, b2;
        if (c < 3) {            // depth-1: issue chunk c+1, named regs
            const int e0 = (c + 1) * 64;
            if (tid < 256) { x0 = *(const float4*)(gA + e0); x1 = *(const float4*)(gA + e0 + 4); }
            b0 = *(const uint4*)(w1aT + (br +   0) * 256 + e0 + bc);
            b1 = *(const uint4*)(w1aT + (br +  64) * 256 + e0 + bc);
            b2 = *(const uint4*)(w1aT + (br + 128) * 256 + e0 + bc);
        }
        const bf16* ab = a_lds + (c & 1) * A32_ELEMS;
        const bf16* bb = b_lds + (c & 1) * B_ELEMS;
#pragma unroll
        for (int ks = 0; ks < 2; ++ks) {
            const int kb = ks * 32 + lk;
            v8s af = *(const v8s*)&ab[(wm * 16 + l15) * 72 + kb];
            v8s bfr[3];
#pragma unroll
            for (int nf = 0; nf < 3; ++nf)
                bfr[nf] = *(const v8s*)&bb[(wn * 48 + nf * 16 + l15) * 72 + kb];
#pragma unroll
            for (int nf = 0; nf < 3; ++nf)
                acc[nf] = MFMA_BF16(af, bfr[nf], acc[nf]);
        }
        if (c < 3) {
            bf16* bdst = b_lds + ((c + 1) & 1) * B_ELEMS;
            if (tid < 256)
                *(v8bf*)(a_lds + ((c + 1) & 1) * A32_ELEMS + aj * 72 + ae) = cvt8(x0, x1);
            *(uint4*)(bdst + (br +   0) * 72 + bc) = b0;
            *(uint4*)(bdst + (br +  64) * 72 + bc) = b1;
            *(uint4*)(bdst + (br + 128) * 72 + bc) = b2;
        }
        __syncthreads();
    }

    {   // layer1 epilogue -> h1
        const float b10 = b1p[wn * 48 + 0  + l15];
        const float b11 = b1p[wn * 48 + 16 + l15];
        const float b12 = b1p[wn * 48 + 32 + l15];
#pragma unroll
        for (int r = 0; r < 4; ++r) {
            const int jl = wm * 16 + (lane >> 4) * 4 + r;
            bf16* hrow = h1_lds + jl * 168 + wn * 48 + l15;
            hrow[0] = (bf16)fmaxf(acc[0][r] + b10, 0.f);
            if (wn < 3) {
                hrow[16] = (bf16)fmaxf(acc[1][r] + b11, 0.f);
                hrow[32] = (bf16)fmaxf(acc[2][r] + b12, 0.f);
            }
        }
    }
    __syncthreads();

    v4f acc2[3];
#pragma unroll
    for (int nf = 0; nf < 3; ++nf) acc2[nf] = (v4f){0.f, 0.f, 0.f, 0.f};
#pragma unroll
    for (int ks = 0; ks < 5; ++ks) {
        const int kb = ks * 32 + lk;
        v8s af = *(const v8s*)&h1_lds[(wm * 16 + l15) * 168 + kb];
        v8s bfr[3];
#pragma unroll
        for (int nf = 0; nf < 3; ++nf)
            bfr[nf] = *(const v8s*)&w2aT[(size_t)(wn * 48 + nf * 16 + l15) * 160 + kb];
#pragma unroll
        for (int nf = 0; nf < 3; ++nf)
            acc2[nf] = MFMA_BF16(af, bfr[nf], acc2[nf]);
    }

    const float b2v0 = b2p[wn * 48 + 0  + l15], w3v0 = w3p[wn * 48 + 0  + l15];
    const float b2v1 = b2p[wn * 48 + 16 + l15], w3v1 = w3p[wn * 48 + 16 + l15];
    const float b2v2 = b2p[wn * 48 + 32 + l15], w3v2 = w3p[wn * 48 + 32 + l15];
#pragma unroll
    for (int r = 0; r < 4; ++r) {
        float p = fmaxf(acc2[0][r] + b2v0, 0.f) * w3v0
                + fmaxf(acc2[1][r] + b2v1, 0.f) * w3v1
                + fmaxf(acc2[2][r] + b2v2, 0.f) * w3v2;
        p += __shfl_xor(p, 1);
        p += __shfl_xor(p, 2);
        p += __shfl_xor(p, 4);
        p += __shfl_xor(p, 8);
        if (l15 == 0) {
            const int jl = wm * 16 + (lane >> 4) * 4 + r;
            red[jl * 4 + wn] = p;
        }
    }
    __syncthreads();
    if (tid < 32) {
        attns[m0 + tid] = red[tid * 4 + 0] + red[tid * 4 + 1]
                        + red[tid * 4 + 2] + red[tid * 4 + 3] + b3[0];
    }
}

// ---------------- uvm: 24 blocks = 3 sections x 8 M-tiles of 32, K=768(NC=12) ----------------
__global__ __launch_bounds__(512, 4) void uvm_mfma_kernel(
    const float* __restrict__ g, const bf16* __restrict__ wuvmT,
    const bf16* __restrict__ w2mT,
    const float* __restrict__ pb1p, const float* __restrict__ mb1p,
    const float* __restrict__ mb2p, const float* __restrict__ mw3p,
    const float* __restrict__ mb3,
    float* __restrict__ u_pad, float* __restrict__ v_pad, float* __restrict__ ment)
{
    __shared__ __attribute__((aligned(16))) char smem[64512];
    bf16*  a_lds  = (bf16*)smem;
    bf16*  b_lds  = (bf16*)(smem + 9216);
    bf16*  h1_lds = (bf16*)smem;
    float* red    = (float*)(smem + 10752);

    const int sect = blockIdx.x >> 3;          // 0=u, 1=v, 2=ment
    const int m0   = (blockIdx.x & 7) * 32;
    const bf16* Bw = wuvmT + (size_t)sect * 147456;
    const int tid = threadIdx.x;
    const int lane = tid & 63;
    const int wm = (tid >> 6) >> 2, wn = (tid >> 6) & 3;
    const int l15 = lane & 15, lk = (lane >> 4) * 8;
    const int aj = tid >> 3, ae = (tid & 7) * 8;
    const int br = tid >> 3, bc = (tid & 7) * 8;
    const float* gA = g + (size_t)(m0 + (aj & 31)) * 768 + ae;

    {   // stage chunk 0
        if (tid < 256) {
            float4 x0 = *(const float4*)(gA + 0), x1 = *(const float4*)(gA + 4);
            *(v8bf*)(a_lds + aj * 72 + ae) = cvt8(x0, x1);
        }
#pragma unroll
        for (int s2 = 0; s2 < 3; ++s2) {
            const int row = br + s2 * 64;
            *(uint4*)(b_lds + row * 72 + bc) = *(const uint4*)(Bw + row * 768 + bc);
        }
    }
    __syncthreads();

    v4f acc[3];
#pragma unroll
    for (int nf = 0; nf < 3; ++nf) acc[nf] = (v4f){0.f, 0.f, 0.f, 0.f};

    for (int c = 0; c < 12; ++c) {
        float4 x0, x1;
        uint4 b0, b1, b2;
        if (c < 11) {
            const int e0 = (c + 1) * 64;
            if (tid < 256) { x0 = *(const float4*)(gA + e0); x1 = *(const float4*)(gA + e0 + 4); }
            b0 = *(const uint4*)(Bw + (br +   0) * 768 + e0 + bc);
            b1 = *(const uint4*)(Bw + (br +  64) * 768 + e0 + bc);
            b2 = *(const uint4*)(Bw + (br + 128) * 768 + e0 + bc);
        }
        const bf16* ab = a_lds + (c & 1) * A32_ELEMS;
        const bf16* bb = b_lds + (c & 1) * B_ELEMS;
#pragma unroll
        for (int ks = 0; ks < 2; ++ks) {
            const int kb = ks * 32 + lk;
            v8s af = *(const v8s*)&ab[(wm * 16 + l15) * 72 + kb];
            v8s bfr[3];
#pragma unroll
            for (int nf = 0; nf < 3; ++nf)
                bfr[nf] = *(const v8s*)&bb[(wn * 48 + nf * 16 + l15) * 72 + kb];
#pragma unroll
            for (int nf = 0; nf < 3; ++nf)
                acc[nf] = MFMA_BF16(af, bfr[nf], acc[nf]);
        }
        if (c < 11) {
            bf16* bdst = b_lds + ((c + 1) & 1) * B_ELEMS;
            if (tid < 256)
                *(v8bf*)(a_lds + ((c + 1) & 1) * A32_ELEMS + aj * 72 + ae) = cvt8(x0, x1);
            *(uint4*)(bdst + (br +   0) * 72 + bc) = b0;
            *(uint4*)(bdst + (br +  64) * 72 + bc) = b1;
            *(uint4*)(bdst + (br + 128) * 72 + bc) = b2;
        }
        __syncthreads();
    }

    if (sect < 2) {
        float* dst = (sect == 0) ? u_pad : v_pad;
        const float bb0 = (sect == 0) ? pb1p[wn * 48 + 0  + l15] : 0.f;
        const float bb1 = (sect == 0) ? pb1p[wn * 48 + 16 + l15] : 0.f;
        const float bb2 = (sect == 0) ? pb1p[wn * 48 + 32 + l15] : 0.f;
#pragma unroll
        for (int r = 0; r < 4; ++r) {
            const int jl = wm * 16 + (lane >> 4) * 4 + r;
            float* drow = dst + (size_t)(m0 + jl) * 192 + wn * 48 + l15;
            drow[0]  = acc[0][r] + bb0;
            drow[16] = acc[1][r] + bb1;
            drow[32] = acc[2][r] + bb2;
        }
        return;
    }

    // ---- ment tail ----
    {
        const float b10 = mb1p[wn * 48 + 0  + l15];
        const float b11 = mb1p[wn * 48 + 16 + l15];
        const float b12 = mb1p[wn * 48 + 32 + l15];
#pragma unroll
        for (int r = 0; r < 4; ++r) {
            const int jl = wm * 16 + (lane >> 4) * 4 + r;
            bf16* hrow = h1_lds + jl * 168 + wn * 48 + l15;
            hrow[0] = (bf16)fmaxf(acc[0][r] + b10, 0.f);
            if (wn < 3) {
                hrow[16] = (bf16)fmaxf(acc[1][r] + b11, 0.f);
                hrow[32] = (bf16)fmaxf(acc[2][r] + b12, 0.f);
            }
        }
    }
    __syncthreads();

    v4f acc2[3];
#pragma unroll
    for (int nf = 0; nf < 3; ++nf) acc2[nf] = (v4f){0.f, 0.f, 0.f, 0.f};
#pragma unroll
    for (int ks = 0; ks < 5; ++ks) {
        const int kb = ks * 32 + lk;
        v8s af = *(const v8s*)&h1_lds[(wm * 16 + l15) * 168 + kb];
        v8s bfr[3];
#pragma unroll
        for (int nf = 0; nf < 3; ++nf)
            bfr[nf] = *(const v8s*)&w2mT[(size_t)(wn * 48 + nf * 16 + l15) * 160 + kb];
#pragma unroll
        for (int nf = 0; nf < 3; ++nf)
            acc2[nf] = MFMA_BF16(af, bfr[nf], acc2[nf]);
    }

    const float b2v0 = mb2p[wn * 48 + 0  + l15], w3v0 = mw3p[wn * 48 + 0  + l15];
    const float b2v1 = mb2p[wn * 48 + 16 + l15], w3v1 = mw3p[wn * 48 + 16 + l15];
    const float b2v2 = mb2p[wn * 48 + 32 + l15], w3v2 = mw3p[wn * 48 + 32 + l15];
#pragma unroll
    for (int r = 0; r < 4; ++r) {
        float p = fmaxf(acc2[0][r] + b2v0, 0.f) * w3v0
                + fmaxf(acc2[1][r] + b2v1, 0.f) * w3v1
                + fmaxf(acc2[2][r] + b2v2, 0.f) * w3v2;
        p += __shfl_xor(p, 1);
        p += __shfl_xor(p, 2);
        p += __shfl_xor(p, 4);
        p += __shfl_xor(p, 8);
        if (l15 == 0) {
            const int jl = wm * 16 + (lane >> 4) * 4 + r;
            red[jl * 4 + wn] = p;
        }
    }
    __syncthreads();
    if (tid < 32) {
        ment[m0 + tid] = red[tid * 4 + 0] + red[tid * 4 + 1]
                       + red[tid * 4 + 2] + red[tid * 4 + 3] + mb3[0];
    }
}

// ---------------- pair: 512 blocks = (b, i, j-half), M=64, depth-1 named regs ----------------
__global__ __launch_bounds__(512, 4) void pair_mfma_kernel(
    const float* __restrict__ g,
    const float* __restrict__ u_pad, const float* __restrict__ v_pad,
    const bf16* __restrict__ w1cT, const bf16* __restrict__ w2T,
    const float* __restrict__ b2_pad, const float* __restrict__ w3_pad,
    const float* __restrict__ pb3, const float* __restrict__ ment,
    float* __restrict__ out)
{
    __shared__ __attribute__((aligned(16))) char smem[76800];
    bf16*  a_lds  = (bf16*)smem;             // 2 x 64 x 72
    bf16*  b_lds  = (bf16*)(smem + 18432);   // 2 x 192 x 72
    float* gi_s   = (float*)(smem + 73728);  // 768 f32
    bf16*  h1_lds = (bf16*)smem;             // [64][168] overlay (21504 B)
    float* red    = (float*)(smem + 22528);

    const int blk = blockIdx.x;              // b*256 + i*2 + half
    const int b = blk >> 8;
    const int i = (blk >> 1) & 127;
    const int half = blk & 1;
    const int row_i = b * 128 + i;
    const int jg0 = b * 128 + half * 64;
    const int tid = threadIdx.x;
    const int lane = tid & 63;
    const int wm = (tid >> 6) >> 2, wn = (tid >> 6) & 3;
    const int l15 = lane & 15, lk = (lane >> 4) * 8;
    const int aj = tid >> 3, ae = (tid & 7) * 8;   // A: row aj (0..63), col ae
    const int br = tid >> 3, bc = (tid & 7) * 8;   // B: rows br,+64,+128, col bc
    const float* gA = g + (size_t)(jg0 + aj) * 768 + ae;

    if (tid < 192)
        *(float4*)&gi_s[tid * 4] = *(const float4*)&g[(size_t)row_i * 768 + tid * 4];
    __syncthreads();

    {   // stage chunk 0
        float4 x0 = *(const float4*)(gA + 0), x1 = *(const float4*)(gA + 4);
        const float* gp = gi_s + ae;
        float4 s0 = *(const float4*)(gp + 0), s1 = *(const float4*)(gp + 4);
        *(v8bf*)(a_lds + aj * 72 + ae) = mul_cvt8(x0, x1, s0, s1);
#pragma unroll
        for (int s2 = 0; s2 < 3; ++s2) {
            const int row = br + s2 * 64;
            *(uint4*)(b_lds + row * 72 + bc) = *(const uint4*)(w1cT + row * 768 + bc);
        }
    }
    __syncthreads();

    v4f acc[2][3];
#pragma unroll
    for (int mf = 0; mf < 2; ++mf)
#pragma unroll
        for (int nf = 0; nf < 3; ++nf) acc[mf][nf] = (v4f){0.f, 0.f, 0.f, 0.f};

    for (int c = 0; c < 12; ++c) {
        float4 x0, x1;
        uint4 b0, b1, b2;
        if (c < 11) {           // depth-1: issue chunk c+1, named regs
            const int e0 = (c + 1) * 64;
            x0 = *(const float4*)(gA + e0);
            x1 = *(const float4*)(gA + e0 + 4);
            b0 = *(const uint4*)(w1cT + (br +   0) * 768 + e0 + bc);
            b1 = *(const uint4*)(w1cT + (br +  64) * 768 + e0 + bc);
            b2 = *(const uint4*)(w1cT + (br + 128) * 768 + e0 + bc);
        }
        const bf16* ab = a_lds + (c & 1) * A64_ELEMS;
        const bf16* bb = b_lds + (c & 1) * B_ELEMS;
#pragma unroll
        for (int ks = 0; ks < 2; ++ks) {
            const int kb = ks * 32 + lk;
            v8s af[2], bfr[3];
#pragma unroll
            for (int mf = 0; mf < 2; ++mf)
                af[mf] = *(const v8s*)&ab[(wm * 32 + mf * 16 + l15) * 72 + kb];
#pragma unroll
            for (int nf = 0; nf < 3; ++nf)
                bfr[nf] = *(const v8s*)&bb[(wn * 48 + nf * 16 + l15) * 72 + kb];
#pragma unroll
            for (int mf = 0; mf < 2; ++mf)
#pragma unroll
                for (int nf = 0; nf < 3; ++nf)
                    acc[mf][nf] = MFMA_BF16(af[mf], bfr[nf], acc[mf][nf]);
        }
        if (c < 11) {
            const float* gp = gi_s + (c + 1) * 64 + ae;
            float4 s0 = *(const float4*)(gp + 0), s1 = *(const float4*)(gp + 4);
            bf16* bdst = b_lds + ((c + 1) & 1) * B_ELEMS;
            *(v8bf*)(a_lds + ((c + 1) & 1) * A64_ELEMS + aj * 72 + ae) =
                mul_cvt8(x0, x1, s0, s1);
            *(uint4*)(bdst + (br +   0) * 72 + bc) = b0;
            *(uint4*)(bdst + (br +  64) * 72 + bc) = b1;
            *(uint4*)(bdst + (br + 128) * 72 + bc) = b2;
        }
        __syncthreads();
    }

    {   // layer1 epilogue: h1 = relu(cross + u_i + v_j)
        const float uh0 = u_pad[row_i * 192 + wn * 48 + 0  + l15];
        const float uh1 = u_pad[row_i * 192 + wn * 48 + 16 + l15];
        const float uh2 = u_pad[row_i * 192 + wn * 48 + 32 + l15];
#pragma unroll
        for (int mf = 0; mf < 2; ++mf) {
#pragma unroll
            for (int r = 0; r < 4; ++r) {
                const int jl = wm * 32 + mf * 16 + (lane >> 4) * 4 + r;
                const float* vrow = v_pad + (size_t)(jg0 + jl) * 192 + wn * 48 + l15;
                const float v0 = acc[mf][0][r] + uh0 + vrow[0];
                const float v1 = acc[mf][1][r] + uh1 + vrow[16];
                const float v2 = acc[mf][2][r] + uh2 + vrow[32];
                bf16* hrow = h1_lds + jl * 168 + wn * 48 + l15;
                hrow[0] = (bf16)fmaxf(v0, 0.f);
                if (wn < 3) {
                    hrow[16] = (bf16)fmaxf(v1, 0.f);
                    hrow[32] = (bf16)fmaxf(v2, 0.f);
                }
            }
        }
    }
    __syncthreads();

    v4f acc2[2][3];
#pragma unroll
    for (int mf = 0; mf < 2; ++mf)
#pragma unroll
        for (int nf = 0; nf < 3; ++nf) acc2[mf][nf] = (v4f){0.f, 0.f, 0.f, 0.f};
#pragma unroll
    for (int ks = 0; ks < 5; ++ks) {
        const int kb = ks * 32 + lk;
        v8s af[2], bfr[3];
#pragma unroll
        for (int mf = 0; mf < 2; ++mf)
            af[mf] = *(const v8s*)&h1_lds[(wm * 32 + mf * 16 + l15) * 168 + kb];
#pragma unroll
        for (int nf = 0; nf < 3; ++nf)
            bfr[nf] = *(const v8s*)&w2T[(size_t)(wn * 48 + nf * 16 + l15) * 160 + kb];
#pragma unroll
        for (int mf = 0; mf < 2; ++mf)
#pragma unroll
            for (int nf = 0; nf < 3; ++nf)
                acc2[mf][nf] = MFMA_BF16(af[mf], bfr[nf], acc2[mf][nf]);
    }

    const float b2v0 = b2_pad[wn * 48 + 0  + l15], w3v0 = w3_pad[wn * 48 + 0  + l15];
    const float b2v1 = b2_pad[wn * 48 + 16 + l15], w3v1 = w3_pad[wn * 48 + 16 + l15];
    const float b2v2 = b2_pad[wn * 48 + 32 + l15], w3v2 = w3_pad[wn * 48 + 32 + l15];
#pragma unroll
    for (int mf = 0; mf < 2; ++mf) {
#pragma unroll
        for (int r = 0; r < 4; ++r) {
            float p = fmaxf(acc2[mf][0][r] + b2v0, 0.f) * w3v0
                    + fmaxf(acc2[mf][1][r] + b2v1, 0.f) * w3v1
                    + fmaxf(acc2[mf][2][r] + b2v2, 0.f) * w3v2;
            p += __shfl_xor(p, 1);
            p += __shfl_xor(p, 2);
            p += __shfl_xor(p, 4);
            p += __shfl_xor(p, 8);
            if (l15 == 0) {
                const int jl = wm * 32 + mf * 16 + (lane >> 4) * 4 + r;
                red[jl * 4 + wn] = p;
            }
        }
    }
    __syncthreads();
    if (tid < 64) {
        const float s = red[tid * 4 + 0] + red[tid * 4 + 1] + red[tid * 4 + 2] + red[tid * 4 + 3];
        out[(size_t)b * 16384 + (size_t)i * 128 + half * 64 + tid] =
            (s + pb3[0] + ment[row_i] + ment[b * 128 + half * 64 + tid]) * (1.f / 3.f);
    }
}

extern "C" void kernel_launch(void* const* d_in, const int* in_sizes, int n_in,
                              void* d_out, int out_size, void* d_ws, size_t ws_size,
                              hipStream_t stream)
{
    const float* emb   = (const float*)d_in[0];
    const int*   spans = (const int*)d_in[1];
    const float* aw1 = (const float*)d_in[2];
    const float* ab1 = (const float*)d_in[3];
    const float* aw2 = (const float*)d_in[4];
    const float* ab2 = (const float*)d_in[5];
    const float* aw3 = (const float*)d_in[6];
    const float* ab3 = (const float*)d_in[7];
    const float* mw1 = (const float*)d_in[8];
    const float* mb1 = (const float*)d_in[9];
    const float* mw2 = (const float*)d_in[10];
    const float* mb2 = (const float*)d_in[11];
    const float* mw3 = (const float*)d_in[12];
    const float* mb3 = (const float*)d_in[13];
    const float* pw1 = (const float*)d_in[14];
    const float* pb1 = (const float*)d_in[15];
    const float* pw2 = (const float*)d_in[16];
    const float* pb2 = (const float*)d_in[17];
    const float* pw3 = (const float*)d_in[18];
    const float* pb3 = (const float*)d_in[19];

    float* ws    = (float*)d_ws;
    float* attns = ws;              // 4096
    float* g     = ws + 4096;       // 196608
    float* ment  = ws + 200704;     // 256
    float* u_pad = ws + 200960;     // 49152
    float* v_pad = ws + 250112;     // 49152
    float* bias  = ws + 299264;     // 1728
    float* pb1p = bias;         float* pb2p = bias + 192;  float* pw3p = bias + 384;
    float* ab1p = bias + 576;   float* ab2p = bias + 768;  float* aw3p = bias + 960;
    float* mb1p = bias + 1152;  float* mb2p = bias + 1344; float* mw3p = bias + 1536;
    bf16* w1cT  = (bf16*)(ws + 300992);
    bf16* w2pT  = (bf16*)(ws + 374720);
    bf16* w1aT  = (bf16*)(ws + 390080);
    bf16* w2aT  = (bf16*)(ws + 414656);
    bf16* w2mT  = (bf16*)(ws + 430016);
    bf16* wuvmT = (bf16*)(ws + 445376);

    prep_kernel<<<2863, 256, 0, stream>>>(pw1, pw2, aw1, aw2, mw1, mw2,
                                          pb1, pb2, pw3, ab1, ab2, aw3, mb1, mb2, mw3,
                                          w1cT, w2pT, w1aT, w2aT, w2mT, wuvmT, bias);
    attn_mfma_kernel<<<128, 512, 0, stream>>>(emb, w1aT, w2aT, ab1p, ab2p, aw3p, ab3, attns);
    build_g_kernel<<<256, 256, 0, stream>>>(emb, spans, attns, g);
    uvm_mfma_kernel<<<24, 512, 0, stream>>>(g, wuvmT, w2mT, pb1p, mb1p, mb2p, mw3p, mb3,
                                            u_pad, v_pad, ment);
    pair_mfma_kernel<<<512, 512, 0, stream>>>(g, u_pad, v_pad, w1cT, w2pT,
                                              pb2p, pw3p, pb3, ment, (float*)d_out);
}

// Round 8
// 57.604 us; speedup vs baseline: 1.8375x; 1.0881x over previous
//
#include <hip/hip_runtime.h>
#include <hip/hip_bf16.h>

// Problem: B=2, T=2048, E=256, S=128, W=8, H=150
// pairs@w1 = gi@w1a + gj@w1b + (gi*gj)@w1c
// All MLP GEMMs on MFMA (bf16 in, f32 acc).
// Round-8: depth-2 K-loop pipeline with NAMED register sets (manual 2x unroll,
// phase A: compute buf0 / write buf1 / issue SET_A; phase B: compute buf1 /
// write buf0 / issue SET_B). No runtime-indexed register arrays (rule #20 —
// round 6's xq[c&1] spilled to scratch, 53MB writes). Math identical to r7.

typedef __bf16 bf16;
typedef __attribute__((ext_vector_type(8))) short v8s;
typedef __attribute__((ext_vector_type(8))) __bf16 v8bf;
typedef __attribute__((ext_vector_type(4))) float v4f;

#define MFMA_BF16(A, B, C) __builtin_amdgcn_mfma_f32_16x16x32_bf16((A), (B), (C), 0, 0, 0)

__device__ __forceinline__ v8bf mul_cvt8(float4 xa, float4 xb, float4 sa, float4 sb) {
    v8bf w;
    w[0] = (bf16)(xa.x * sa.x); w[1] = (bf16)(xa.y * sa.y);
    w[2] = (bf16)(xa.z * sa.z); w[3] = (bf16)(xa.w * sa.w);
    w[4] = (bf16)(xb.x * sb.x); w[5] = (bf16)(xb.y * sb.y);
    w[6] = (bf16)(xb.z * sb.z); w[7] = (bf16)(xb.w * sb.w);
    return w;
}
__device__ __forceinline__ v8bf cvt8(float4 xa, float4 xb) {
    v8bf w;
    w[0] = (bf16)xa.x; w[1] = (bf16)xa.y; w[2] = (bf16)xa.z; w[3] = (bf16)xa.w;
    w[4] = (bf16)xb.x; w[5] = (bf16)xb.y; w[6] = (bf16)xb.z; w[7] = (bf16)xb.w;
    return w;
}

// ---------------- prep (unchanged) ----------------
__global__ __launch_bounds__(256) void prep_kernel(
    const float* __restrict__ pw1, const float* __restrict__ pw2,
    const float* __restrict__ aw1, const float* __restrict__ aw2,
    const float* __restrict__ mw1, const float* __restrict__ mw2,
    const float* __restrict__ pb1, const float* __restrict__ pb2, const float* __restrict__ pw3,
    const float* __restrict__ ab1, const float* __restrict__ ab2, const float* __restrict__ aw3,
    const float* __restrict__ mb1, const float* __restrict__ mb2, const float* __restrict__ mw3,
    bf16* __restrict__ w1cT, bf16* __restrict__ w2pT,
    bf16* __restrict__ w1aT, bf16* __restrict__ w2aT, bf16* __restrict__ w2mT,
    bf16* __restrict__ wuvmT, float* __restrict__ bias)
{
    int idx = blockIdx.x * 256 + threadIdx.x;
    if (idx < 147456) {
        int h = idx / 768, e = idx % 768;
        w1cT[idx] = (bf16)((h < 150) ? pw1[(1536 + e) * 150 + h] : 0.f);
    } else if (idx < 178176) {
        int j = idx - 147456; int n = j / 160, k = j % 160;
        w2pT[j] = (bf16)((n < 150 && k < 150) ? pw2[k * 150 + n] : 0.f);
    } else if (idx < 227328) {
        int j = idx - 178176; int h = j / 256, e = j % 256;
        w1aT[j] = (bf16)((h < 150) ? aw1[e * 150 + h] : 0.f);
    } else if (idx < 258048) {
        int j = idx - 227328; int n = j / 160, k = j % 160;
        w2aT[j] = (bf16)((n < 150 && k < 150) ? aw2[k * 150 + n] : 0.f);
    } else if (idx < 288768) {
        int j = idx - 258048; int n = j / 160, k = j % 160;
        w2mT[j] = (bf16)((n < 150 && k < 150) ? mw2[k * 150 + n] : 0.f);
    } else if (idx < 731136) {
        int j = idx - 288768; int s = j / 147456; int r = j % 147456;
        int h = r / 768, e = r % 768;
        float v = 0.f;
        if (h < 150) {
            if (s == 0)      v = pw1[e * 150 + h];
            else if (s == 1) v = pw1[(768 + e) * 150 + h];
            else             v = mw1[e * 150 + h];
        }
        wuvmT[j] = (bf16)v;
    } else if (idx < 732864) {
        int j = idx - 731136; int arr = j / 192, h = j % 192;
        const float* src;
        switch (arr) {
            case 0: src = pb1; break; case 1: src = pb2; break; case 2: src = pw3; break;
            case 3: src = ab1; break; case 4: src = ab2; break; case 5: src = aw3; break;
            case 6: src = mb1; break; case 7: src = mb2; break; default: src = mw3; break;
        }
        bias[j] = (h < 150) ? src[h] : 0.f;
    }
}

// ---------------- build g (unchanged) ----------------
__global__ __launch_bounds__(256) void build_g_kernel(
    const float* __restrict__ emb, const int* __restrict__ spans,
    const float* __restrict__ attns, float* __restrict__ g)
{
    int blk = blockIdx.x;
    int b = blk >> 7;
    int t0 = spans[blk];
    int e = threadIdx.x;
    const float* eb = emb + ((size_t)(b * 2048 + t0)) * 256 + e;
    const float* at = attns + b * 2048 + t0;
    float start = eb[0];
    float endv  = eb[7 * 256];
    float wsum = 0.f;
#pragma unroll
    for (int w = 0; w < 8; ++w) wsum = fmaf(eb[w * 256], at[w], wsum);
    g[(size_t)blk * 768 + e]       = start;
    g[(size_t)blk * 768 + 256 + e] = endv;
    g[(size_t)blk * 768 + 512 + e] = wsum;
}

#define A32_ELEMS 2304   // 32*72
#define A64_ELEMS 4608   // 64*72
#define B_ELEMS   13824  // 192*72

// ---------------- attn MLP: 128 blocks, M=32, K=256(NC=4), N=192pad ----------------
__global__ __launch_bounds__(512, 4) void attn_mfma_kernel(
    const float* __restrict__ emb,
    const bf16* __restrict__ w1aT, const bf16* __restrict__ w2aT,
    const float* __restrict__ b1p, const float* __restrict__ b2p,
    const float* __restrict__ w3p, const float* __restrict__ b3,
    float* __restrict__ attns)
{
    __shared__ __attribute__((aligned(16))) char smem[64512];
    bf16*  a_lds  = (bf16*)smem;              // 2 x 32 x 72
    bf16*  b_lds  = (bf16*)(smem + 9216);     // 2 x 192 x 72
    bf16*  h1_lds = (bf16*)smem;              // [32][168] overlay (10752 B)
    float* red    = (float*)(smem + 10752);

    const int m0  = blockIdx.x * 32;
    const int tid = threadIdx.x;
    const int lane = tid & 63;
    const int wm = (tid >> 6) >> 2, wn = (tid >> 6) & 3;
    const int l15 = lane & 15, lk = (lane >> 4) * 8;
    const int aj = tid >> 3, ae = (tid & 7) * 8;
    const int br = tid >> 3, bc = (tid & 7) * 8;
    const float* gA = emb + (size_t)(m0 + (aj & 31)) * 256 + ae;

    v4f acc[3];
#pragma unroll
    for (int nf = 0; nf < 3; ++nf) acc[nf] = (v4f){0.f, 0.f, 0.f, 0.f};

#define ATTN_COMPUTE(AB, BB)                                                   \
    do {                                                                       \
        _Pragma("unroll")                                                      \
        for (int ks = 0; ks < 2; ++ks) {                                       \
            const int kb = ks * 32 + lk;                                       \
            v8s af = *(const v8s*)&(AB)[(wm * 16 + l15) * 72 + kb];            \
            v8s bf0 = *(const v8s*)&(BB)[(wn * 48 +  0 + l15) * 72 + kb];      \
            v8s bf1 = *(const v8s*)&(BB)[(wn * 48 + 16 + l15) * 72 + kb];      \
            v8s bf2 = *(const v8s*)&(BB)[(wn * 48 + 32 + l15) * 72 + kb];      \
            acc[0] = MFMA_BF16(af, bf0, acc[0]);                               \
            acc[1] = MFMA_BF16(af, bf1, acc[1]);                               \
            acc[2] = MFMA_BF16(af, bf2, acc[2]);                               \
        }                                                                      \
    } while (0)

    {   // prologue: stage chunk 0 into buf0
        if (tid < 256) {
            float4 x0 = *(const float4*)(gA + 0), x1 = *(const float4*)(gA + 4);
            *(v8bf*)(a_lds + aj * 72 + ae) = cvt8(x0, x1);
        }
#pragma unroll
        for (int s2 = 0; s2 < 3; ++s2) {
            const int row = br + s2 * 64;
            *(uint4*)(b_lds + row * 72 + bc) = *(const uint4*)(w1aT + row * 256 + bc);
        }
    }
    float4 xB0, xB1; uint4 bB0, bB1, bB2;   // SET B: chunk 1
    if (tid < 256) { xB0 = *(const float4*)(gA + 64); xB1 = *(const float4*)(gA + 68); }
    bB0 = *(const uint4*)(w1aT + (br +   0) * 256 + 64 + bc);
    bB1 = *(const uint4*)(w1aT + (br +  64) * 256 + 64 + bc);
    bB2 = *(const uint4*)(w1aT + (br + 128) * 256 + 64 + bc);
    __syncthreads();

    float4 xA0, xA1; uint4 bA0, bA1, bA2;   // SET A
    for (int cc = 0; cc < 2; ++cc) {
        const int c = cc * 2;
        // ---- phase A: compute chunk c (buf0); write chunk c+1 (SET B)->buf1 ----
        if (cc < 1) {
            const int e0 = (c + 2) * 64;
            if (tid < 256) { xA0 = *(const float4*)(gA + e0); xA1 = *(const float4*)(gA + e0 + 4); }
            bA0 = *(const uint4*)(w1aT + (br +   0) * 256 + e0 + bc);
            bA1 = *(const uint4*)(w1aT + (br +  64) * 256 + e0 + bc);
            bA2 = *(const uint4*)(w1aT + (br + 128) * 256 + e0 + bc);
        }
        ATTN_COMPUTE(a_lds, b_lds);
        if (tid < 256)
            *(v8bf*)(a_lds + A32_ELEMS + aj * 72 + ae) = cvt8(xB0, xB1);
        *(uint4*)(b_lds + B_ELEMS + (br +   0) * 72 + bc) = bB0;
        *(uint4*)(b_lds + B_ELEMS + (br +  64) * 72 + bc) = bB1;
        *(uint4*)(b_lds + B_ELEMS + (br + 128) * 72 + bc) = bB2;
        __syncthreads();
        // ---- phase B: compute chunk c+1 (buf1); write chunk c+2 (SET A)->buf0 ----
        if (cc < 1) {
            const int e0 = (c + 3) * 64;
            if (tid < 256) { xB0 = *(const float4*)(gA + e0); xB1 = *(const float4*)(gA + e0 + 4); }
            bB0 = *(const uint4*)(w1aT + (br +   0) * 256 + e0 + bc);
            bB1 = *(const uint4*)(w1aT + (br +  64) * 256 + e0 + bc);
            bB2 = *(const uint4*)(w1aT + (br + 128) * 256 + e0 + bc);
        }
        ATTN_COMPUTE(a_lds + A32_ELEMS, b_lds + B_ELEMS);
        if (cc < 1) {
            if (tid < 256)
                *(v8bf*)(a_lds + aj * 72 + ae) = cvt8(xA0, xA1);
            *(uint4*)(b_lds + (br +   0) * 72 + bc) = bA0;
            *(uint4*)(b_lds + (br +  64) * 72 + bc) = bA1;
            *(uint4*)(b_lds + (br + 128) * 72 + bc) = bA2;
        }
        __syncthreads();
    }

    {   // layer1 epilogue -> h1
        const float b10 = b1p[wn * 48 + 0  + l15];
        const float b11 = b1p[wn * 48 + 16 + l15];
        const float b12 = b1p[wn * 48 + 32 + l15];
#pragma unroll
        for (int r = 0; r < 4; ++r) {
            const int jl = wm * 16 + (lane >> 4) * 4 + r;
            bf16* hrow = h1_lds + jl * 168 + wn * 48 + l15;
            hrow[0] = (bf16)fmaxf(acc[0][r] + b10, 0.f);
            if (wn < 3) {
                hrow[16] = (bf16)fmaxf(acc[1][r] + b11, 0.f);
                hrow[32] = (bf16)fmaxf(acc[2][r] + b12, 0.f);
            }
        }
    }
    __syncthreads();

    v4f acc2[3];
#pragma unroll
    for (int nf = 0; nf < 3; ++nf) acc2[nf] = (v4f){0.f, 0.f, 0.f, 0.f};
#pragma unroll
    for (int ks = 0; ks < 5; ++ks) {
        const int kb = ks * 32 + lk;
        v8s af = *(const v8s*)&h1_lds[(wm * 16 + l15) * 168 + kb];
        v8s bfr[3];
#pragma unroll
        for (int nf = 0; nf < 3; ++nf)
            bfr[nf] = *(const v8s*)&w2aT[(size_t)(wn * 48 + nf * 16 + l15) * 160 + kb];
#pragma unroll
        for (int nf = 0; nf < 3; ++nf)
            acc2[nf] = MFMA_BF16(af, bfr[nf], acc2[nf]);
    }

    const float b2v0 = b2p[wn * 48 + 0  + l15], w3v0 = w3p[wn * 48 + 0  + l15];
    const float b2v1 = b2p[wn * 48 + 16 + l15], w3v1 = w3p[wn * 48 + 16 + l15];
    const float b2v2 = b2p[wn * 48 + 32 + l15], w3v2 = w3p[wn * 48 + 32 + l15];
#pragma unroll
    for (int r = 0; r < 4; ++r) {
        float p = fmaxf(acc2[0][r] + b2v0, 0.f) * w3v0
                + fmaxf(acc2[1][r] + b2v1, 0.f) * w3v1
                + fmaxf(acc2[2][r] + b2v2, 0.f) * w3v2;
        p += __shfl_xor(p, 1);
        p += __shfl_xor(p, 2);
        p += __shfl_xor(p, 4);
        p += __shfl_xor(p, 8);
        if (l15 == 0) {
            const int jl = wm * 16 + (lane >> 4) * 4 + r;
            red[jl * 4 + wn] = p;
        }
    }
    __syncthreads();
    if (tid < 32) {
        attns[m0 + tid] = red[tid * 4 + 0] + red[tid * 4 + 1]
                        + red[tid * 4 + 2] + red[tid * 4 + 3] + b3[0];
    }
}

// ---------------- uvm: 24 blocks = 3 sections x 8 M-tiles of 32, K=768(NC=12) ----------------
__global__ __launch_bounds__(512, 4) void uvm_mfma_kernel(
    const float* __restrict__ g, const bf16* __restrict__ wuvmT,
    const bf16* __restrict__ w2mT,
    const float* __restrict__ pb1p, const float* __restrict__ mb1p,
    const float* __restrict__ mb2p, const float* __restrict__ mw3p,
    const float* __restrict__ mb3,
    float* __restrict__ u_pad, float* __restrict__ v_pad, float* __restrict__ ment)
{
    __shared__ __attribute__((aligned(16))) char smem[64512];
    bf16*  a_lds  = (bf16*)smem;
    bf16*  b_lds  = (bf16*)(smem + 9216);
    bf16*  h1_lds = (bf16*)smem;
    float* red    = (float*)(smem + 10752);

    const int sect = blockIdx.x >> 3;          // 0=u, 1=v, 2=ment
    const int m0   = (blockIdx.x & 7) * 32;
    const bf16* Bw = wuvmT + (size_t)sect * 147456;
    const int tid = threadIdx.x;
    const int lane = tid & 63;
    const int wm = (tid >> 6) >> 2, wn = (tid >> 6) & 3;
    const int l15 = lane & 15, lk = (lane >> 4) * 8;
    const int aj = tid >> 3, ae = (tid & 7) * 8;
    const int br = tid >> 3, bc = (tid & 7) * 8;
    const float* gA = g + (size_t)(m0 + (aj & 31)) * 768 + ae;

    v4f acc[3];
#pragma unroll
    for (int nf = 0; nf < 3; ++nf) acc[nf] = (v4f){0.f, 0.f, 0.f, 0.f};

    {   // prologue: stage chunk 0 into buf0
        if (tid < 256) {
            float4 x0 = *(const float4*)(gA + 0), x1 = *(const float4*)(gA + 4);
            *(v8bf*)(a_lds + aj * 72 + ae) = cvt8(x0, x1);
        }
#pragma unroll
        for (int s2 = 0; s2 < 3; ++s2) {
            const int row = br + s2 * 64;
            *(uint4*)(b_lds + row * 72 + bc) = *(const uint4*)(Bw + row * 768 + bc);
        }
    }
    float4 xB0, xB1; uint4 bB0, bB1, bB2;   // SET B: chunk 1
    if (tid < 256) { xB0 = *(const float4*)(gA + 64); xB1 = *(const float4*)(gA + 68); }
    bB0 = *(const uint4*)(Bw + (br +   0) * 768 + 64 + bc);
    bB1 = *(const uint4*)(Bw + (br +  64) * 768 + 64 + bc);
    bB2 = *(const uint4*)(Bw + (br + 128) * 768 + 64 + bc);
    __syncthreads();

    float4 xA0, xA1; uint4 bA0, bA1, bA2;
    for (int cc = 0; cc < 6; ++cc) {
        const int c = cc * 2;
        // ---- phase A ----
        if (cc < 5) {
            const int e0 = (c + 2) * 64;
            if (tid < 256) { xA0 = *(const float4*)(gA + e0); xA1 = *(const float4*)(gA + e0 + 4); }
            bA0 = *(const uint4*)(Bw + (br +   0) * 768 + e0 + bc);
            bA1 = *(const uint4*)(Bw + (br +  64) * 768 + e0 + bc);
            bA2 = *(const uint4*)(Bw + (br + 128) * 768 + e0 + bc);
        }
        ATTN_COMPUTE(a_lds, b_lds);
        if (tid < 256)
            *(v8bf*)(a_lds + A32_ELEMS + aj * 72 + ae) = cvt8(xB0, xB1);
        *(uint4*)(b_lds + B_ELEMS + (br +   0) * 72 + bc) = bB0;
        *(uint4*)(b_lds + B_ELEMS + (br +  64) * 72 + bc) = bB1;
        *(uint4*)(b_lds + B_ELEMS + (br + 128) * 72 + bc) = bB2;
        __syncthreads();
        // ---- phase B ----
        if (cc < 5) {
            const int e0 = (c + 3) * 64;
            if (tid < 256) { xB0 = *(const float4*)(gA + e0); xB1 = *(const float4*)(gA + e0 + 4); }
            bB0 = *(const uint4*)(Bw + (br +   0) * 768 + e0 + bc);
            bB1 = *(const uint4*)(Bw + (br +  64) * 768 + e0 + bc);
            bB2 = *(const uint4*)(Bw + (br + 128) * 768 + e0 + bc);
        }
        ATTN_COMPUTE(a_lds + A32_ELEMS, b_lds + B_ELEMS);
        if (cc < 5) {
            if (tid < 256)
                *(v8bf*)(a_lds + aj * 72 + ae) = cvt8(xA0, xA1);
            *(uint4*)(b_lds + (br +   0) * 72 + bc) = bA0;
            *(uint4*)(b_lds + (br +  64) * 72 + bc) = bA1;
            *(uint4*)(b_lds + (br + 128) * 72 + bc) = bA2;
        }
        __syncthreads();
    }

    if (sect < 2) {
        float* dst = (sect == 0) ? u_pad : v_pad;
        const float bb0 = (sect == 0) ? pb1p[wn * 48 + 0  + l15] : 0.f;
        const float bb1 = (sect == 0) ? pb1p[wn * 48 + 16 + l15] : 0.f;
        const float bb2 = (sect == 0) ? pb1p[wn * 48 + 32 + l15] : 0.f;
#pragma unroll
        for (int r = 0; r < 4; ++r) {
            const int jl = wm * 16 + (lane >> 4) * 4 + r;
            float* drow = dst + (size_t)(m0 + jl) * 192 + wn * 48 + l15;
            drow[0]  = acc[0][r] + bb0;
            drow[16] = acc[1][r] + bb1;
            drow[32] = acc[2][r] + bb2;
        }
        return;
    }

    // ---- ment tail ----
    {
        const float b10 = mb1p[wn * 48 + 0  + l15];
        const float b11 = mb1p[wn * 48 + 16 + l15];
        const float b12 = mb1p[wn * 48 + 32 + l15];
#pragma unroll
        for (int r = 0; r < 4; ++r) {
            const int jl = wm * 16 + (lane >> 4) * 4 + r;
            bf16* hrow = h1_lds + jl * 168 + wn * 48 + l15;
            hrow[0] = (bf16)fmaxf(acc[0][r] + b10, 0.f);
            if (wn < 3) {
                hrow[16] = (bf16)fmaxf(acc[1][r] + b11, 0.f);
                hrow[32] = (bf16)fmaxf(acc[2][r] + b12, 0.f);
            }
        }
    }
    __syncthreads();

    v4f acc2[3];
#pragma unroll
    for (int nf = 0; nf < 3; ++nf) acc2[nf] = (v4f){0.f, 0.f, 0.f, 0.f};
#pragma unroll
    for (int ks = 0; ks < 5; ++ks) {
        const int kb = ks * 32 + lk;
        v8s af = *(const v8s*)&h1_lds[(wm * 16 + l15) * 168 + kb];
        v8s bfr[3];
#pragma unroll
        for (int nf = 0; nf < 3; ++nf)
            bfr[nf] = *(const v8s*)&w2mT[(size_t)(wn * 48 + nf * 16 + l15) * 160 + kb];
#pragma unroll
        for (int nf = 0; nf < 3; ++nf)
            acc2[nf] = MFMA_BF16(af, bfr[nf], acc2[nf]);
    }

    const float b2v0 = mb2p[wn * 48 + 0  + l15], w3v0 = mw3p[wn * 48 + 0  + l15];
    const float b2v1 = mb2p[wn * 48 + 16 + l15], w3v1 = mw3p[wn * 48 + 16 + l15];
    const float b2v2 = mb2p[wn * 48 + 32 + l15], w3v2 = mw3p[wn * 48 + 32 + l15];
#pragma unroll
    for (int r = 0; r < 4; ++r) {
        float p = fmaxf(acc2[0][r] + b2v0, 0.f) * w3v0
                + fmaxf(acc2[1][r] + b2v1, 0.f) * w3v1
                + fmaxf(acc2[2][r] + b2v2, 0.f) * w3v2;
        p += __shfl_xor(p, 1);
        p += __shfl_xor(p, 2);
        p += __shfl_xor(p, 4);
        p += __shfl_xor(p, 8);
        if (l15 == 0) {
            const int jl = wm * 16 + (lane >> 4) * 4 + r;
            red[jl * 4 + wn] = p;
        }
    }
    __syncthreads();
    if (tid < 32) {
        ment[m0 + tid] = red[tid * 4 + 0] + red[tid * 4 + 1]
                       + red[tid * 4 + 2] + red[tid * 4 + 3] + mb3[0];
    }
}

// ---------------- pair: 512 blocks = (b, i, j-half), M=64, depth-2 named sets ----------------
__global__ __launch_bounds__(512, 4) void pair_mfma_kernel(
    const float* __restrict__ g,
    const float* __restrict__ u_pad, const float* __restrict__ v_pad,
    const bf16* __restrict__ w1cT, const bf16* __restrict__ w2T,
    const float* __restrict__ b2_pad, const float* __restrict__ w3_pad,
    const float* __restrict__ pb3, const float* __restrict__ ment,
    float* __restrict__ out)
{
    __shared__ __attribute__((aligned(16))) char smem[76800];
    bf16*  a_lds  = (bf16*)smem;             // 2 x 64 x 72
    bf16*  b_lds  = (bf16*)(smem + 18432);   // 2 x 192 x 72
    float* gi_s   = (float*)(smem + 73728);  // 768 f32
    bf16*  h1_lds = (bf16*)smem;             // [64][168] overlay (21504 B)
    float* red    = (float*)(smem + 22528);

    const int blk = blockIdx.x;              // b*256 + i*2 + half
    const int b = blk >> 8;
    const int i = (blk >> 1) & 127;
    const int half = blk & 1;
    const int row_i = b * 128 + i;
    const int jg0 = b * 128 + half * 64;
    const int tid = threadIdx.x;
    const int lane = tid & 63;
    const int wm = (tid >> 6) >> 2, wn = (tid >> 6) & 3;
    const int l15 = lane & 15, lk = (lane >> 4) * 8;
    const int aj = tid >> 3, ae = (tid & 7) * 8;
    const int br = tid >> 3, bc = (tid & 7) * 8;
    const float* gA = g + (size_t)(jg0 + aj) * 768 + ae;

    if (tid < 192)
        *(float4*)&gi_s[tid * 4] = *(const float4*)&g[(size_t)row_i * 768 + tid * 4];
    __syncthreads();

    v4f acc[2][3];
#pragma unroll
    for (int mf = 0; mf < 2; ++mf)
#pragma unroll
        for (int nf = 0; nf < 3; ++nf) acc[mf][nf] = (v4f){0.f, 0.f, 0.f, 0.f};

#define PAIR_COMPUTE(AB, BB)                                                   \
    do {                                                                       \
        _Pragma("unroll")                                                      \
        for (int ks = 0; ks < 2; ++ks) {                                       \
            const int kb = ks * 32 + lk;                                       \
            v8s af0 = *(const v8s*)&(AB)[(wm * 32 +  0 + l15) * 72 + kb];      \
            v8s af1 = *(const v8s*)&(AB)[(wm * 32 + 16 + l15) * 72 + kb];      \
            v8s bf0 = *(const v8s*)&(BB)[(wn * 48 +  0 + l15) * 72 + kb];      \
            v8s bf1 = *(const v8s*)&(BB)[(wn * 48 + 16 + l15) * 72 + kb];      \
            v8s bf2 = *(const v8s*)&(BB)[(wn * 48 + 32 + l15) * 72 + kb];      \
            acc[0][0] = MFMA_BF16(af0, bf0, acc[0][0]);                        \
            acc[0][1] = MFMA_BF16(af0, bf1, acc[0][1]);                        \
            acc[0][2] = MFMA_BF16(af0, bf2, acc[0][2]);                        \
            acc[1][0] = MFMA_BF16(af1, bf0, acc[1][0]);                        \
            acc[1][1] = MFMA_BF16(af1, bf1, acc[1][1]);                        \
            acc[1][2] = MFMA_BF16(af1, bf2, acc[1][2]);                        \
        }                                                                      \
    } while (0)

    {   // prologue: stage chunk 0 into buf0
        float4 x0 = *(const float4*)(gA + 0), x1 = *(const float4*)(gA + 4);
        const float* gp = gi_s + ae;
        float4 s0 = *(const float4*)(gp + 0), s1 = *(const float4*)(gp + 4);
        *(v8bf*)(a_lds + aj * 72 + ae) = mul_cvt8(x0, x1, s0, s1);
#pragma unroll
        for (int s2 = 0; s2 < 3; ++s2) {
            const int row = br + s2 * 64;
            *(uint4*)(b_lds + row * 72 + bc) = *(const uint4*)(w1cT + row * 768 + bc);
        }
    }
    float4 xB0, xB1; uint4 bB0, bB1, bB2;   // SET B: chunk 1
    xB0 = *(const float4*)(gA + 64);
    xB1 = *(const float4*)(gA + 68);
    bB0 = *(const uint4*)(w1cT + (br +   0) * 768 + 64 + bc);
    bB1 = *(const uint4*)(w1cT + (br +  64) * 768 + 64 + bc);
    bB2 = *(const uint4*)(w1cT + (br + 128) * 768 + 64 + bc);
    __syncthreads();

    float4 xA0, xA1; uint4 bA0, bA1, bA2;
    for (int cc = 0; cc < 6; ++cc) {
        const int c = cc * 2;
        // ---- phase A: compute chunk c (buf0); write chunk c+1 (SET B)->buf1 ----
        if (cc < 5) {
            const int e0 = (c + 2) * 64;
            xA0 = *(const float4*)(gA + e0);
            xA1 = *(const float4*)(gA + e0 + 4);
            bA0 = *(const uint4*)(w1cT + (br +   0) * 768 + e0 + bc);
            bA1 = *(const uint4*)(w1cT + (br +  64) * 768 + e0 + bc);
            bA2 = *(const uint4*)(w1cT + (br + 128) * 768 + e0 + bc);
        }
        PAIR_COMPUTE(a_lds, b_lds);
        {
            const float* gp = gi_s + (c + 1) * 64 + ae;
            float4 s0 = *(const float4*)(gp + 0), s1 = *(const float4*)(gp + 4);
            *(v8bf*)(a_lds + A64_ELEMS + aj * 72 + ae) = mul_cvt8(xB0, xB1, s0, s1);
            *(uint4*)(b_lds + B_ELEMS + (br +   0) * 72 + bc) = bB0;
            *(uint4*)(b_lds + B_ELEMS + (br +  64) * 72 + bc) = bB1;
            *(uint4*)(b_lds + B_ELEMS + (br + 128) * 72 + bc) = bB2;
        }
        __syncthreads();
        // ---- phase B: compute chunk c+1 (buf1); write chunk c+2 (SET A)->buf0 ----
        if (cc < 5) {
            const int e0 = (c + 3) * 64;
            xB0 = *(const float4*)(gA + e0);
            xB1 = *(const float4*)(gA + e0 + 4);
            bB0 = *(const uint4*)(w1cT + (br +   0) * 768 + e0 + bc);
            bB1 = *(const uint4*)(w1cT + (br +  64) * 768 + e0 + bc);
            bB2 = *(const uint4*)(w1cT + (br + 128) * 768 + e0 + bc);
        }
        PAIR_COMPUTE(a_lds + A64_ELEMS, b_lds + B_ELEMS);
        if (cc < 5) {
            const float* gp = gi_s + (c + 2) * 64 + ae;
            float4 s0 = *(const float4*)(gp + 0), s1 = *(const float4*)(gp + 4);
            *(v8bf*)(a_lds + aj * 72 + ae) = mul_cvt8(xA0, xA1, s0, s1);
            *(uint4*)(b_lds + (br +   0) * 72 + bc) = bA0;
            *(uint4*)(b_lds + (br +  64) * 72 + bc) = bA1;
            *(uint4*)(b_lds + (br + 128) * 72 + bc) = bA2;
        }
        __syncthreads();
    }

    {   // layer1 epilogue: h1 = relu(cross + u_i + v_j)
        const float uh0 = u_pad[row_i * 192 + wn * 48 + 0  + l15];
        const float uh1 = u_pad[row_i * 192 + wn * 48 + 16 + l15];
        const float uh2 = u_pad[row_i * 192 + wn * 48 + 32 + l15];
#pragma unroll
        for (int mf = 0; mf < 2; ++mf) {
#pragma unroll
            for (int r = 0; r < 4; ++r) {
                const int jl = wm * 32 + mf * 16 + (lane >> 4) * 4 + r;
                const float* vrow = v_pad + (size_t)(jg0 + jl) * 192 + wn * 48 + l15;
                const float v0 = acc[mf][0][r] + uh0 + vrow[0];
                const float v1 = acc[mf][1][r] + uh1 + vrow[16];
                const float v2 = acc[mf][2][r] + uh2 + vrow[32];
                bf16* hrow = h1_lds + jl * 168 + wn * 48 + l15;
                hrow[0] = (bf16)fmaxf(v0, 0.f);
                if (wn < 3) {
                    hrow[16] = (bf16)fmaxf(v1, 0.f);
                    hrow[32] = (bf16)fmaxf(v2, 0.f);
                }
            }
        }
    }
    __syncthreads();

    v4f acc2[2][3];
#pragma unroll
    for (int mf = 0; mf < 2; ++mf)
#pragma unroll
        for (int nf = 0; nf < 3; ++nf) acc2[mf][nf] = (v4f){0.f, 0.f, 0.f, 0.f};
#pragma unroll
    for (int ks = 0; ks < 5; ++ks) {
        const int kb = ks * 32 + lk;
        v8s af[2], bfr[3];
#pragma unroll
        for (int mf = 0; mf < 2; ++mf)
            af[mf] = *(const v8s*)&h1_lds[(wm * 32 + mf * 16 + l15) * 168 + kb];
#pragma unroll
        for (int nf = 0; nf < 3; ++nf)
            bfr[nf] = *(const v8s*)&w2T[(size_t)(wn * 48 + nf * 16 + l15) * 160 + kb];
#pragma unroll
        for (int mf = 0; mf < 2; ++mf)
#pragma unroll
            for (int nf = 0; nf < 3; ++nf)
                acc2[mf][nf] = MFMA_BF16(af[mf], bfr[nf], acc2[mf][nf]);
    }

    const float b2v0 = b2_pad[wn * 48 + 0  + l15], w3v0 = w3_pad[wn * 48 + 0  + l15];
    const float b2v1 = b2_pad[wn * 48 + 16 + l15], w3v1 = w3_pad[wn * 48 + 16 + l15];
    const float b2v2 = b2_pad[wn * 48 + 32 + l15], w3v2 = w3_pad[wn * 48 + 32 + l15];
#pragma unroll
    for (int mf = 0; mf < 2; ++mf) {
#pragma unroll
        for (int r = 0; r < 4; ++r) {
            float p = fmaxf(acc2[mf][0][r] + b2v0, 0.f) * w3v0
                    + fmaxf(acc2[mf][1][r] + b2v1, 0.f) * w3v1
                    + fmaxf(acc2[mf][2][r] + b2v2, 0.f) * w3v2;
            p += __shfl_xor(p, 1);
            p += __shfl_xor(p, 2);
            p += __shfl_xor(p, 4);
            p += __shfl_xor(p, 8);
            if (l15 == 0) {
                const int jl = wm * 32 + mf * 16 + (lane >> 4) * 4 + r;
                red[jl * 4 + wn] = p;
            }
        }
    }
    __syncthreads();
    if (tid < 64) {
        const float s = red[tid * 4 + 0] + red[tid * 4 + 1] + red[tid * 4 + 2] + red[tid * 4 + 3];
        out[(size_t)b * 16384 + (size_t)i * 128 + half * 64 + tid] =
            (s + pb3[0] + ment[row_i] + ment[b * 128 + half * 64 + tid]) * (1.f / 3.f);
    }
}

extern "C" void kernel_launch(void* const* d_in, const int* in_sizes, int n_in,
                              void* d_out, int out_size, void* d_ws, size_t ws_size,
                              hipStream_t stream)
{
    const float* emb   = (const float*)d_in[0];
    const int*   spans = (const int*)d_in[1];
    const float* aw1 = (const float*)d_in[2];
    const float* ab1 = (const float*)d_in[3];
    const float* aw2 = (const float*)d_in[4];
    const float* ab2 = (const float*)d_in[5];
    const float* aw3 = (const float*)d_in[6];
    const float* ab3 = (const float*)d_in[7];
    const float* mw1 = (const float*)d_in[8];
    const float* mb1 = (const float*)d_in[9];
    const float* mw2 = (const float*)d_in[10];
    const float* mb2 = (const float*)d_in[11];
    const float* mw3 = (const float*)d_in[12];
    const float* mb3 = (const float*)d_in[13];
    const float* pw1 = (const float*)d_in[14];
    const float* pb1 = (const float*)d_in[15];
    const float* pw2 = (const float*)d_in[16];
    const float* pb2 = (const float*)d_in[17];
    const float* pw3 = (const float*)d_in[18];
    const float* pb3 = (const float*)d_in[19];

    float* ws    = (float*)d_ws;
    float* attns = ws;              // 4096
    float* g     = ws + 4096;       // 196608
    float* ment  = ws + 200704;     // 256
    float* u_pad = ws + 200960;     // 49152
    float* v_pad = ws + 250112;     // 49152
    float* bias  = ws + 299264;     // 1728
    float* pb1p = bias;         float* pb2p = bias + 192;  float* pw3p = bias + 384;
    float* ab1p = bias + 576;   float* ab2p = bias + 768;  float* aw3p = bias + 960;
    float* mb1p = bias + 1152;  float* mb2p = bias + 1344; float* mw3p = bias + 1536;
    bf16* w1cT  = (bf16*)(ws + 300992);
    bf16* w2pT  = (bf16*)(ws + 374720);
    bf16* w1aT  = (bf16*)(ws + 390080);
    bf16* w2aT  = (bf16*)(ws + 414656);
    bf16* w2mT  = (bf16*)(ws + 430016);
    bf16* wuvmT = (bf16*)(ws + 445376);

    prep_kernel<<<2863, 256, 0, stream>>>(pw1, pw2, aw1, aw2, mw1, mw2,
                                          pb1, pb2, pw3, ab1, ab2, aw3, mb1, mb2, mw3,
                                          w1cT, w2pT, w1aT, w2aT, w2mT, wuvmT, bias);
    attn_mfma_kernel<<<128, 512, 0, stream>>>(emb, w1aT, w2aT, ab1p, ab2p, aw3p, ab3, attns);
    build_g_kernel<<<256, 256, 0, stream>>>(emb, spans, attns, g);
    uvm_mfma_kernel<<<24, 512, 0, stream>>>(g, wuvmT, w2mT, pb1p, mb1p, mb2p, mw3p, mb3,
                                            u_pad, v_pad, ment);
    pair_mfma_kernel<<<512, 512, 0, stream>>>(g, u_pad, v_pad, w1cT, w2pT,
                                              pb2p, pw3p, pb3, ment, (float*)d_out);
}